// Round 9
// baseline (4186.575 us; speedup 1.0000x reference)
//
#include <hip/hip_runtime.h>
#include <hip/hip_bf16.h>

using bf16 = __hip_bfloat16;
typedef __attribute__((ext_vector_type(8))) short short8;
typedef __attribute__((ext_vector_type(4))) float f32x4;

#define DEVI __device__ __forceinline__

#define MTOT 16384      // 64 * 16 * 16 output positions
#define PADS 25600      // 64 * 20 * 20 padded positions

DEVI float sigm_(float x){ return 1.f/(1.f+expf(-x)); }

// padded spatial index (row) for interior position m = ((nb*16)+iy)*16+ix
DEVI long pidx_(int m){
  int nb = m>>8, iy=(m>>4)&15, ix=m&15;
  return (long)(nb*20 + iy + 2)*20 + (ix + 2);
}

// async global->LDS, 16B per lane. LDS dest = wave-uniform base + lane*16.
DEVI void async16(const void* g, void* l) {
  __builtin_amdgcn_global_load_lds(
      (__attribute__((address_space(1))) void*)(unsigned long long)g,
      (__attribute__((address_space(3))) void*)(unsigned int)(unsigned long long)l,
      16, 0, 0);
}

// fused counted-vmcnt wait + barrier (single asm so no loads slip between)
template<int N> DEVI void waitbar(){
  if constexpr (N==0)      asm volatile("s_waitcnt vmcnt(0)\ns_barrier" ::: "memory");
  else if constexpr (N==3) asm volatile("s_waitcnt vmcnt(3)\ns_barrier" ::: "memory");
  else                     asm volatile("s_waitcnt vmcnt(6)\ns_barrier" ::: "memory");
}

// ---------------------------------------------------------------------------
// 3-blocks/CU gates GEMM. BM=256, BN=128, BK=32, 8 waves 4Mx2N (64x64/wave).
// DOUBLE-buffered LDS (48KB -> 3 blocks/CU at 144KB), split-K=3 via blockIdx.z,
// grid (64,4,3)=768 blocks = exactly 3/CU. vmcnt(0)+barrier per subtile is a
// no-op stall: loads are issued a full phase (~1900cy) ahead of their wait,
// >> 900cy HBM latency. Race-safety: DMA of buf[(t+1)&1] issued post-barrier;
// every wave's reads of that buffer completed before its previous MFMA, which
// precedes that barrier. Natural m-major order: XCD = m0&7 -> the 12 (n,z)
// copies of each m-tile share one XCD's L2 (1.7MB A footprint, r7-proven).
// Output: bf16 PARTIAL planes stride 512, no bias (summed in lstm3_k).
// ---------------------------------------------------------------------------
template<int CA>
__global__ __launch_bounds__(512)
void conv_split3(const bf16* __restrict__ A, const bf16* __restrict__ Bt,
                 bf16* __restrict__ P0, bf16* __restrict__ P1, bf16* __restrict__ P2)
{
  constexpr int Kp = 25*CA;
  constexpr int NSUB = Kp/32;
  constexpr int q = NSUB/3, r = NSUB%3;
  __shared__ alignas(16) bf16 As[2][256*32];   // 16KB each
  __shared__ alignas(16) bf16 Bs[2][128*32];   // 8KB each

  const int z = blockIdx.z;
  const int s0 = z*q + (z < r ? z : r);
  const int NS = q + (z < r ? 1 : 0);
  bf16* __restrict__ P = (z==0) ? P0 : ((z==1) ? P1 : P2);

  const int m0 = blockIdx.x<<8;
  const int n0 = blockIdx.y<<7;
  const int tid = threadIdx.x;
  const int wv = tid>>6, ln = tid&63;

  // staging: A 256x32 = 1024 chunks of 16B (thread t -> chunks t, t+512);
  // B 128x32 = 512. row = chunk>>2; phys chunk holds logical chunk^((row>>1)&3)
  // via pre-swizzled global source (0 LDS conflicts, measured r2-r8).
  const int rA = tid>>2;
  const int qs = ((tid&3) ^ ((rA>>1)&3))<<3;
  const int mA0 = m0 + rA, mA1 = m0 + 128 + rA;
  const long paA0 = ((long)(((mA0>>8)*20 + ((mA0>>4)&15))*20 + (mA0&15)))*CA + qs;
  const long paA1 = ((long)(((mA1>>8)*20 + ((mA1>>4)&15))*20 + (mA1&15)))*CA + qs;
  const long pbB  = (long)(n0 + rA)*Kp + qs;

  // K-cursor from s0
  int kk0 = s0*32;
  int c0 = kk0 % CA;
  int tap = kk0 / CA;
  int kh = tap/5, kw = tap%5;
  int ks = kk0;

  auto stage = [&](int d){
    const long sh = (long)(kh*20 + kw)*CA + c0;
    char* la = (char*)(&As[d][0]) + (wv<<10);
    char* lb = (char*)(&Bs[d][0]) + (wv<<10);
    async16(A + paA0 + sh, la);
    async16(A + paA1 + sh, la + 8192);
    async16(Bt + pbB + ks, lb);
    ks += 32;
    c0 += 32; if (c0==CA){ c0=0; if(++kw==5){kw=0; ++kh;} }
  };

  f32x4 acc[4][4] = {};
  const int wm = wv>>1, wn = wv&1;
  const int rowA = (wm<<6) + (ln&15);
  const int rowB = (wn<<6) + (ln&15);
  const int kqA = (((ln>>4) ^ ((rowA>>1)&3))<<4);
  const int kqB = (((ln>>4) ^ ((rowB>>1)&3))<<4);

  stage(0);
  for (int t=0; t<NS; ++t) {
    waitbar<0>();                 // stage(t) landed (issued 1 phase ago) + sync
    if (t+1 < NS) stage((t+1)&1); // overwrites buffer released at the barrier

    const char* as_ = (const char*)(&As[t&1][0]);
    const char* bs_ = (const char*)(&Bs[t&1][0]);
    short8 af[4], bfr[4];
    #pragma unroll
    for (int mf=0; mf<4; mf++)
      af[mf] = *(const short8*)(as_ + ((rowA + (mf<<4))<<6) + kqA);
    #pragma unroll
    for (int nf=0; nf<4; nf++)
      bfr[nf] = *(const short8*)(bs_ + ((rowB + (nf<<4))<<6) + kqB);
    __builtin_amdgcn_s_setprio(1);
    #pragma unroll
    for (int mf=0; mf<4; mf++)
      #pragma unroll
      for (int nf=0; nf<4; nf++)
        acc[mf][nf] = __builtin_amdgcn_mfma_f32_16x16x32_bf16(af[mf], bfr[nf], acc[mf][nf], 0,0,0);
    __builtin_amdgcn_s_setprio(0);
  }

  const int mb = m0 + (wm<<6);
  const int nb = n0 + (wn<<6);
  const int ml = (ln>>4)<<2;
  const int nl = ln&15;
  #pragma unroll
  for (int mf=0; mf<4; mf++) {
    #pragma unroll
    for (int j=0; j<4; j++) {
      const int m = mb + (mf<<4) + ml + j;
      #pragma unroll
      for (int nf=0; nf<4; nf++) {
        const int n = nb + (nf<<4) + nl;
        P[((long)m<<9) + n] = __float2bfloat16(acc[mf][nf][j]);
      }
    }
  }
}

// ---------------------------------------------------------------------------
// r7-proven 8-wave conv body (BM=256, BN=128, BK=32, triple-buffer, depth-2,
// counted vmcnt(3), setprio). Used by conv_tp (2 blocks/CU) and conv_post.
// EPI: 2 = s_enc: bf16 padded stride 416, +b(n<394) +ST +h_dec(n<128)
//      4 = fused decT+prior: n<352 -> sDec (+b(n<327)+ST); n>=384 -> PriorO f32
//      6 = bf16 PARTIAL out stride 128, no bias            [split-K post]
// ---------------------------------------------------------------------------
template<int CA, int EPI>
DEVI void conv_body(const bf16* __restrict__ A, const bf16* __restrict__ Bt,
                    const float* __restrict__ bias, const float* __restrict__ bias2,
                    float* __restrict__ outF, bf16* __restrict__ outB,
                    const bf16* __restrict__ ST, const bf16* __restrict__ extra,
                    int s0, int s1, int m0, int n0,
                    bf16* AsBase, bf16* BsBase)
{
  constexpr int Kp = 25*CA;
  const int NS = s1 - s0;

  const int tid = threadIdx.x;
  const int wv = tid>>6, ln = tid&63;

  const int rA = tid>>2;
  const int qs = ((tid&3) ^ ((rA>>1)&3))<<3;
  const int mA0 = m0 + rA, mA1 = m0 + 128 + rA;
  const long paA0 = ((long)(((mA0>>8)*20 + ((mA0>>4)&15))*20 + (mA0&15)))*CA + qs;
  const long paA1 = ((long)(((mA1>>8)*20 + ((mA1>>4)&15))*20 + (mA1&15)))*CA + qs;
  const long pbB  = (long)(n0 + rA)*Kp + qs;

  int kk0 = s0*32;
  int c0 = kk0 % CA;
  int tap = kk0 / CA;
  int kh = tap/5, kw = tap%5;
  int ks = kk0;

  auto stage = [&](int d){
    const long sh = (long)(kh*20 + kw)*CA + c0;
    char* la = (char*)AsBase + d*16384 + (wv<<10);
    char* lb = (char*)BsBase + d*8192  + (wv<<10);
    async16(A + paA0 + sh, la);
    async16(A + paA1 + sh, la + 8192);
    async16(Bt + pbB + ks, lb);
    ks += 32;
    c0 += 32; if (c0==CA){ c0=0; if(++kw==5){kw=0; ++kh;} }
  };

  f32x4 acc[4][4] = {};
  const int wm = wv>>1, wn = wv&1;
  const int rowA = (wm<<6) + (ln&15);
  const int rowB = (wn<<6) + (ln&15);
  const int kqA = (((ln>>4) ^ ((rowA>>1)&3))<<4);
  const int kqB = (((ln>>4) ^ ((rowB>>1)&3))<<4);

  stage(0); stage(1);
  int bc = 0, bs = 2;
  for (int t=0; t<NS; ++t) {
    if (t+1 < NS) waitbar<3>();
    else          waitbar<0>();
    if (t+2 < NS) stage(bs);

    const char* as_ = (const char*)AsBase + bc*16384;
    const char* bs_ = (const char*)BsBase + bc*8192;
    short8 af[4], bfr[4];
    #pragma unroll
    for (int mf=0; mf<4; mf++)
      af[mf] = *(const short8*)(as_ + ((rowA + (mf<<4))<<6) + kqA);
    #pragma unroll
    for (int nf=0; nf<4; nf++)
      bfr[nf] = *(const short8*)(bs_ + ((rowB + (nf<<4))<<6) + kqB);
    __builtin_amdgcn_s_setprio(1);
    #pragma unroll
    for (int mf=0; mf<4; mf++)
      #pragma unroll
      for (int nf=0; nf<4; nf++)
        acc[mf][nf] = __builtin_amdgcn_mfma_f32_16x16x32_bf16(af[mf], bfr[nf], acc[mf][nf], 0,0,0);
    __builtin_amdgcn_s_setprio(0);
    bc = (bc==2)?0:bc+1; bs = (bs==2)?0:bs+1;
  }

  const int mb = m0 + (wm<<6);
  const int nb = n0 + (wn<<6);
  const int ml = (ln>>4)<<2;
  const int nl = ln&15;
  #pragma unroll
  for (int mf=0; mf<4; mf++) {
    #pragma unroll
    for (int j=0; j<4; j++) {
      const int m = mb + (mf<<4) + ml + j;
      const long pI = pidx_(m);
      #pragma unroll
      for (int nf=0; nf<4; nf++) {
        const int n = nb + (nf<<4) + nl;
        const float v = acc[mf][nf][j];
        if constexpr (EPI==2) {
          if (n < 416) {
            float b  = (n < 394) ? bias[n] : 0.f;
            float st = __bfloat162float(ST[(long)m*416 + n]);
            float e  = (n < 128) ? __bfloat162float(extra[(pI<<7) + n]) : 0.f;
            outB[pI*416 + n] = __float2bfloat16(v + b + st + e);
          }
        } else if constexpr (EPI==4) {
          if (n < 352) {
            float b  = (n < 327) ? bias[n] : 0.f;
            float st = __bfloat162float(ST[(long)m*352 + n]);
            outB[pI*352 + n] = __float2bfloat16(v + b + st);
          } else if (n >= 384) {
            outF[((long)m<<7) + (n-384)] = v + bias2[n-384];
          }
        } else { // EPI==6: split-K partial, stride 128, no bias
          outB[((long)m<<7) + n] = __float2bfloat16(v);
        }
      }
    }
  }
}

// merged decT+prior (z=0) and encT (z=1): independent convs, 2 blocks/CU.
__global__ __launch_bounds__(512)
void conv_tp(const bf16* __restrict__ hDec, const bf16* __restrict__ BtDP,
             const float* __restrict__ dec_tb, const float* __restrict__ prior_b,
             float* __restrict__ PriorO, bf16* __restrict__ sDec,
             const bf16* __restrict__ STdec,
             const bf16* __restrict__ hEnc, const bf16* __restrict__ BtEncT,
             const float* __restrict__ enc_tb, bf16* __restrict__ sEnc,
             const bf16* __restrict__ STenc)
{
  __shared__ alignas(16) bf16 As[3][256*32];
  __shared__ alignas(16) bf16 Bs[3][128*32];
  const int m0 = blockIdx.x<<8, n0 = blockIdx.y<<7;
  if (blockIdx.z == 0)
    conv_body<128,4>(hDec, BtDP, dec_tb, prior_b, PriorO, sDec, STdec, nullptr,
                     0, 100, m0, n0, &As[0][0], &Bs[0][0]);
  else
    conv_body<128,2>(hEnc, BtEncT, enc_tb, nullptr, nullptr, sEnc, STenc, hDec,
                     0, 100, m0, n0, &As[0][0], &Bs[0][0]);
}

// post GEMM split-K=4: grid (64,1,4); partial planes of 16384x128 bf16.
__global__ __launch_bounds__(512)
void conv_post(const bf16* __restrict__ hEnc, const bf16* __restrict__ BtPost,
               bf16* __restrict__ PP)
{
  __shared__ alignas(16) bf16 As[3][256*32];
  __shared__ alignas(16) bf16 Bs[3][128*32];
  const int z = blockIdx.z;
  conv_body<128,6>(hEnc, BtPost, nullptr, nullptr, nullptr,
                   PP + (long)z*MTOT*128, nullptr, nullptr,
                   z*25, z*25+25, blockIdx.x<<8, 0, &As[0][0], &Bs[0][0]);
}

// OIHW f32 -> Bt[n=o][k=(kh*5+kw)*CA + c] bf16, rows o>=O and cols c>=I zeroed.
__global__ void repack_w_k(const float* __restrict__ w, bf16* __restrict__ Bt,
                           int O, int I, int CA, long total)
{
  long e = (long)blockIdx.x*256 + threadIdx.x;
  if (e >= total) return;
  const int Kp = 25*CA;
  int o = (int)(e / Kp);
  int k = (int)(e % Kp);
  int blk = k / CA, c = k % CA;
  int kh = blk / 5, kwi = blk % 5;
  float v = 0.f;
  if (o < O && c < I) v = w[((long)o*I + c)*25 + kh*5 + kwi];
  Bt[e] = __float2bfloat16(v);
}

// Wcomb[c][pix*3+o] = sum_m write_w[c,m,ki,kj] * obs_w[o,m]   (pix = ki*4+kj)
__global__ void wcomb_k(const float* __restrict__ ww, const float* __restrict__ ow,
                        float* __restrict__ Wc)
{
  int idx = blockIdx.x*256 + threadIdx.x;
  if (idx >= 128*48) return;
  int c = idx / 48, rst = idx % 48;
  int pix = rst / 3, o = rst % 3;
  int ki = pix >> 2, kj = pix & 3;
  float a = 0.f;
  for (int mm=0; mm<128; mm++)
    a += ww[(((long)c*128 + mm)*4 + ki)*4 + kj] * ow[o*128 + mm];
  Wc[idx] = a;
}

// xr = conv(x, read_w, stride 4), xr[m*3+o]
__global__ void xr_k(const float* __restrict__ x, const float* __restrict__ rw,
                     float* __restrict__ xr)
{
  int idx = blockIdx.x*256 + threadIdx.x;
  if (idx >= MTOT*3) return;
  int m = idx / 3, o = idx % 3;
  int nb = m>>8, iy=(m>>4)&15, ix=m&15;
  float a = 0.f;
  for (int c=0;c<3;c++)
    for (int kh=0;kh<4;kh++)
      for (int kw=0;kw<4;kw++)
        a += x[((long)(nb*3+c)*64 + (iy*4+kh))*64 + (ix*4+kw)] * rw[((o*3+c)*4+kh)*4+kw];
  xr[idx] = a;
}

// static concat part for enc: channels 128..393 of ST_enc (stride 416)
__global__ void st_enc_k(const float* __restrict__ xr, const float* __restrict__ v,
                         const float* __restrict__ r, bf16* __restrict__ ST)
{
  long g = (long)blockIdx.x*256 + threadIdx.x;
  if (g >= (long)MTOT*266) return;
  int m = (int)(g / 266), ch = (int)(g % 266);
  int nb = m>>8, sp = m&255;
  float val;
  if (ch < 3)       val = xr[m*3 + ch];
  else if (ch < 10) val = v[nb*7 + ch - 3];
  else              val = r[((long)nb*256 + (ch-10))*256 + sp];
  ST[(long)m*416 + 128 + ch] = __float2bfloat16(val);
}

// static concat part for dec: channels 64..326 of ST_dec (stride 352)
__global__ void st_dec_k(const float* __restrict__ v, const float* __restrict__ r,
                         bf16* __restrict__ ST)
{
  long g = (long)blockIdx.x*256 + threadIdx.x;
  if (g >= (long)MTOT*263) return;
  int m = (int)(g / 263), ch = (int)(g % 263);
  int nb = m>>8, sp = m&255;
  float val;
  if (ch < 7) val = v[nb*7 + ch];
  else        val = r[((long)nb*256 + (ch-7))*256 + sp];
  ST[(long)m*352 + 64 + ch] = __float2bfloat16(val);
}

// LSTM pointwise over 3 split-K partials: gates = P0+P1+P2+bias (f,i,o,s)
__global__ void lstm3_k(const bf16* __restrict__ P0, const bf16* __restrict__ P1,
                        const bf16* __restrict__ P2, const float* __restrict__ gb_,
                        float* __restrict__ cbuf, bf16* __restrict__ hpad)
{
  int idx = blockIdx.x*256 + threadIdx.x;   // exactly MTOT*128
  int m = idx >> 7, c = idx & 127;
  long gb = (long)m << 9;
  float f = __bfloat162float(P0[gb + c])       + __bfloat162float(P1[gb + c])
          + __bfloat162float(P2[gb + c])       + gb_[c];
  float i = __bfloat162float(P0[gb + 128 + c]) + __bfloat162float(P1[gb + 128 + c])
          + __bfloat162float(P2[gb + 128 + c]) + gb_[128 + c];
  float o = __bfloat162float(P0[gb + 256 + c]) + __bfloat162float(P1[gb + 256 + c])
          + __bfloat162float(P2[gb + 256 + c]) + gb_[256 + c];
  float s = __bfloat162float(P0[gb + 384 + c]) + __bfloat162float(P1[gb + 384 + c])
          + __bfloat162float(P2[gb + 384 + c]) + gb_[384 + c];
  float cell = sigm_(f)*cbuf[idx] + sigm_(i)*tanhf(s);
  cbuf[idx] = cell;
  hpad[(pidx_(m)<<7) + c] = __float2bfloat16(sigm_(o)*tanhf(cell));
}

// z = q_mu + exp(0.5 q_lv)*eps with q = sum of 4 post partials + bias;
// ADD z into sDec ch 0..63 ; KL partial per block (no contended atomics)
__global__ void zkl4_k(const bf16* __restrict__ PP, const float* __restrict__ pb,
                       const float* __restrict__ prior, const float* __restrict__ eps_t,
                       bf16* __restrict__ sDec, float* __restrict__ part)
{
  __shared__ float wsum[4];
  const long PL = (long)MTOT*128;
  int idx = blockIdx.x*256 + threadIdx.x;   // exactly MTOT*64
  int m = idx >> 6, c = idx & 63;
  float qm = pb[c], ql = pb[64 + c];
  #pragma unroll
  for (int z=0; z<4; ++z) {
    qm += __bfloat162float(PP[z*PL + ((long)m<<7) + c]);
    ql += __bfloat162float(PP[z*PL + ((long)m<<7) + 64 + c]);
  }
  long pbx = (long)m << 7;
  float pm = prior[pbx + c], pl = prior[pbx + 64 + c];
  int nb = m>>8, sp = m&255;
  float e = eps_t[((long)nb*64 + c)*256 + sp];
  float z = qm + expf(0.5f*ql)*e;
  long so = pidx_(m)*352 + c;
  sDec[so] = __float2bfloat16(__bfloat162float(sDec[so]) + z);
  float kl = expf(ql - pl) + (pm-qm)*(pm-qm)*expf(-pl) - 1.f + (pl - ql);
  #pragma unroll
  for (int off=32; off>0; off>>=1) kl += __shfl_down(kl, off);
  if ((threadIdx.x & 63) == 0) wsum[threadIdx.x >> 6] = kl;
  __syncthreads();
  if (threadIdx.x == 0)
    part[blockIdx.x] = wsum[0] + wsum[1] + wsum[2] + wsum[3];
}

// canvas pre-activation accumulate: uc[n,y,x,o] += sum_c h_dec*Wcomb
__global__ __launch_bounds__(256)
void wrc_k(const bf16* __restrict__ hpad, const float* __restrict__ Wc,
           float* __restrict__ uc)
{
  __shared__ float Wl[128*48];
  for (int i = threadIdx.x; i < 128*48; i += 256) Wl[i] = Wc[i];
  __syncthreads();
  int t = threadIdx.x;
  int mloc = t >> 4, pix = t & 15;
  int m = (blockIdx.x<<4) + mloc;
  int nb = m>>8, iy=(m>>4)&15, ix=m&15;
  const bf16* h = hpad + (pidx_(m)<<7);
  float a0=0.f, a1=0.f, a2=0.f;
  for (int c=0;c<128;c++) {
    float hv = __bfloat162float(h[c]);
    const float* wl = Wl + c*48 + pix*3;
    a0 += hv*wl[0]; a1 += hv*wl[1]; a2 += hv*wl[2];
  }
  int ki = pix>>2, kj = pix&3;
  long ob = ((long)((nb<<6) + (iy<<2) + ki)*64 + (ix<<2) + kj)*3;
  uc[ob+0] += a0; uc[ob+1] += a1; uc[ob+2] += a2;
}

__global__ void canvas_k(const float* __restrict__ uc, const float* __restrict__ ob,
                         float* __restrict__ out)
{
  int idx = blockIdx.x*256 + threadIdx.x;   // exactly 786432, NCHW order
  int x = idx & 63, y = (idx>>6)&63;
  int rem = idx >> 12;
  int o = rem % 3, n = rem / 3;
  float v = uc[((long)((n<<6)+y)*64 + x)*3 + o] + ob[o];
  out[idx] = 1.f/(1.f+expf(-v));
}

// final KL: sum 8*4096 per-block partials, scale, write out[786432]
__global__ void klred_k(const float* __restrict__ part, float* __restrict__ out)
{
  __shared__ float wsum[4];
  float a = 0.f;
  for (int i = threadIdx.x; i < 32768; i += 256) a += part[i];
  #pragma unroll
  for (int off=32; off>0; off>>=1) a += __shfl_down(a, off);
  if ((threadIdx.x & 63) == 0) wsum[threadIdx.x >> 6] = a;
  __syncthreads();
  if (threadIdx.x == 0)
    out[786432] = (wsum[0] + wsum[1] + wsum[2] + wsum[3]) * (0.5f/64.f);
}

// ---------------------------------------------------------------------------
// workspace layout (bytes). Gate partial planes P0/P1/P2 (3 x 16.7MB); PostP
// (4 x 4.2MB = 16.7MB) ALIASES plane 0 — lifetimes are disjoint within an
// iteration (gates planes live around lstm3; PostP lives conv_post..zkl4).
static const long O_BT_POST  = 0;                     // 128*3200*2
static const long O_BT_ENCT  = O_BT_POST  + 819200;   // 512*3200*2
static const long O_BT_DP    = O_BT_ENCT  + 3276800;  // 512*3200*2
static const long O_BT_ENCG  = O_BT_DP    + 3276800;  // 512*10400*2
static const long O_BT_DECG  = O_BT_ENCG  + 10649600; // 512*8800*2
static const long O_WCOMB    = O_BT_DECG  + 9011200;  // 6144*4
static const long O_XR       = O_WCOMB    + 24576;    // 49152*4
static const long O_KLP      = O_XR       + 196608;   // 32768*4
static const long O_STENC    = O_KLP      + 131072;   // 16384*416*2
static const long O_STDEC    = O_STENC    + 13631488; // 16384*352*2
static const long O_HENC     = O_STDEC    + 11534336; // 25600*128*2
static const long O_HDEC     = O_HENC     + 6553600;
static const long O_SENC     = O_HDEC     + 6553600;  // 25600*416*2
static const long O_SDEC     = O_SENC     + 21299200; // 25600*352*2
static const long O_CENC     = O_SDEC     + 18022400; // 16384*128*4
static const long O_CDEC     = O_CENC     + 8388608;
static const long O_PRIOR    = O_CDEC     + 8388608;  // 16384*128*4
static const long O_PG       = O_PRIOR    + 8388608;  // 3 x 16777216
static const long O_UC       = O_PG       + 50331648; // 786432*4
static const long WS_TOTAL   = O_UC       + 3145728;  // ~183.5 MB

extern "C" void kernel_launch(void* const* d_in, const int* in_sizes, int n_in,
                              void* d_out, int out_size, void* d_ws, size_t ws_size,
                              hipStream_t stream)
{
  const float* x       = (const float*)d_in[0];
  const float* v       = (const float*)d_in[1];
  const float* r       = (const float*)d_in[2];
  const float* eps     = (const float*)d_in[3];
  const float* read_w  = (const float*)d_in[4];
  const float* write_w = (const float*)d_in[5];
  const float* prior_w = (const float*)d_in[6];
  const float* prior_b = (const float*)d_in[7];
  const float* post_w  = (const float*)d_in[8];
  const float* post_b  = (const float*)d_in[9];
  const float* enc_gw  = (const float*)d_in[10];
  const float* enc_gb  = (const float*)d_in[11];
  const float* enc_tw  = (const float*)d_in[12];
  const float* enc_tb  = (const float*)d_in[13];
  const float* dec_gw  = (const float*)d_in[14];
  const float* dec_gb  = (const float*)d_in[15];
  const float* dec_tw  = (const float*)d_in[16];
  const float* dec_tb  = (const float*)d_in[17];
  const float* obs_w   = (const float*)d_in[18];
  const float* obs_b   = (const float*)d_in[19];

  char* ws = (char*)d_ws;
  bf16* BtPost  = (bf16*)(ws + O_BT_POST);
  bf16* BtEncT  = (bf16*)(ws + O_BT_ENCT);
  bf16* BtDP    = (bf16*)(ws + O_BT_DP);
  bf16* BtEncG  = (bf16*)(ws + O_BT_ENCG);
  bf16* BtDecG  = (bf16*)(ws + O_BT_DECG);
  float* Wcomb  = (float*)(ws + O_WCOMB);
  float* XR     = (float*)(ws + O_XR);
  float* KLpart = (float*)(ws + O_KLP);
  bf16* STenc   = (bf16*)(ws + O_STENC);
  bf16* STdec   = (bf16*)(ws + O_STDEC);
  bf16* hEnc    = (bf16*)(ws + O_HENC);
  bf16* hDec    = (bf16*)(ws + O_HDEC);
  bf16* sEnc    = (bf16*)(ws + O_SENC);
  bf16* sDec    = (bf16*)(ws + O_SDEC);
  float* cEnc   = (float*)(ws + O_CENC);
  float* cDec   = (float*)(ws + O_CDEC);
  float* PriorO = (float*)(ws + O_PRIOR);
  bf16* P0      = (bf16*)(ws + O_PG);
  bf16* P1      = (bf16*)(ws + O_PG + 16777216);
  bf16* P2      = (bf16*)(ws + O_PG + 33554432);
  bf16* PostP   = (bf16*)(ws + O_PG);            // aliases P0 (disjoint lifetime)
  float* Ucomb  = (float*)(ws + O_UC);
  float* out    = (float*)d_out;

  size_t clr = (size_t)WS_TOTAL; if (clr > ws_size) clr = ws_size;
  hipMemsetAsync(d_ws, 0, clr, stream);

  // weight repacks
  repack_w_k<<<1600, 256, 0, stream>>>(post_w,  BtPost, 128, 128, 128, 128L*3200);
  repack_w_k<<<6400, 256, 0, stream>>>(enc_tw,  BtEncT, 394, 128, 128, 512L*3200);
  repack_w_k<<<4800, 256, 0, stream>>>(dec_tw,  BtDP,   327, 128, 128, 384L*3200);
  repack_w_k<<<1600, 256, 0, stream>>>(prior_w, BtDP + 384L*3200, 128, 128, 128, 128L*3200);
  repack_w_k<<<20800,256, 0, stream>>>(enc_gw,  BtEncG, 512, 394, 416, 512L*10400);
  repack_w_k<<<17600,256, 0, stream>>>(dec_gw,  BtDecG, 512, 327, 352, 512L*8800);
  wcomb_k<<<24, 256, 0, stream>>>(write_w, obs_w, Wcomb);
  xr_k<<<192, 256, 0, stream>>>(x, read_w, XR);
  st_enc_k<<<(int)(((long)MTOT*266 + 255)/256), 256, 0, stream>>>(XR, v, r, STenc);
  st_dec_k<<<(int)(((long)MTOT*263 + 255)/256), 256, 0, stream>>>(v, r, STdec);

  for (int t = 0; t < 8; ++t) {
    // merged: z=0 sDec=decT(hDec)+tb+ST & PriorO ; z=1 sEnc=encT(hEnc)+tb+ST+hDec
    conv_tp<<<dim3(64,4,2), 512, 0, stream>>>(
        hDec, BtDP, dec_tb, prior_b, PriorO, sDec, STdec,
        hEnc, BtEncT, enc_tb, sEnc, STenc);
    // enc gates: split-K=3, 3 blocks/CU
    conv_split3<416><<<dim3(64,4,3), 512, 0, stream>>>(sEnc, BtEncG, P0, P1, P2);
    lstm3_k<<<8192, 256, 0, stream>>>(P0, P1, P2, enc_gb, cEnc, hEnc);
    // post split-K=4 -> partial planes (alias of P0; gates planes are dead now)
    conv_post<<<dim3(64,1,4), 512, 0, stream>>>(hEnc, BtPost, PostP);
    // z (sum partials + bias) -> add into sDec ch0..63 ; KL partials
    zkl4_k<<<4096, 256, 0, stream>>>(PostP, post_b, PriorO,
                                     eps + (long)t*64*64*256, sDec,
                                     KLpart + (long)t*4096);
    // dec gates: split-K=3
    conv_split3<352><<<dim3(64,4,3), 512, 0, stream>>>(sDec, BtDecG, P0, P1, P2);
    lstm3_k<<<8192, 256, 0, stream>>>(P0, P1, P2, dec_gb, cDec, hDec);
    // canvas accumulate (write conv fused with obs 1x1)
    wrc_k<<<1024, 256, 0, stream>>>(hDec, Wcomb, Ucomb);
  }

  canvas_k<<<3072, 256, 0, stream>>>(Ucomb, obs_b, out);
  klred_k<<<1, 256, 0, stream>>>(KLpart, out);
}

// Round 10
// 3980.173 us; speedup vs baseline: 1.0519x; 1.0519x over previous
//
#include <hip/hip_runtime.h>
#include <hip/hip_bf16.h>

using bf16 = __hip_bfloat16;
typedef __attribute__((ext_vector_type(8))) short short8;
typedef __attribute__((ext_vector_type(4))) float f32x4;

#define DEVI __device__ __forceinline__

#define MTOT 16384      // 64 * 16 * 16 output positions
#define PADS 25600      // 64 * 20 * 20 padded positions

DEVI float sigm_(float x){ return 1.f/(1.f+expf(-x)); }

// padded spatial index (row) for interior position m = ((nb*16)+iy)*16+ix
DEVI long pidx_(int m){
  int nb = m>>8, iy=(m>>4)&15, ix=m&15;
  return (long)(nb*20 + iy + 2)*20 + (ix + 2);
}

// async global->LDS, 16B per lane. LDS dest = wave-uniform base + lane*16.
DEVI void async16(const void* g, void* l) {
  __builtin_amdgcn_global_load_lds(
      (__attribute__((address_space(1))) void*)(unsigned long long)g,
      (__attribute__((address_space(3))) void*)(unsigned int)(unsigned long long)l,
      16, 0, 0);
}

// fused counted-vmcnt wait + barrier (single asm so no loads slip between)
template<int N> DEVI void waitbar(){
  if constexpr (N==0)      asm volatile("s_waitcnt vmcnt(0)\ns_barrier" ::: "memory");
  else if constexpr (N==3) asm volatile("s_waitcnt vmcnt(3)\ns_barrier" ::: "memory");
  else                     asm volatile("s_waitcnt vmcnt(6)\ns_barrier" ::: "memory");
}

// ---------------------------------------------------------------------------
// r7-proven 8-wave conv body. BM=256, BN=128, BK=32, triple-buffered LDS
// (72KB -> exactly 2 blocks/CU), prefetch depth 2, counted vmcnt(3), setprio.
// Natural m-major block order (XCD = x&7 clusters the n/z copies of each
// m-tile on one XCD -> 25-tap A re-reads hit L2; do NOT XCD-swizzle).
// EPI: 2 = s_enc: bf16 padded stride 416, +b(n<394) +ST +h_dec(n<128)
//      4 = fused decT+prior: n<352 -> sDec (+b(n<327)+ST); n>=384 -> PriorO f32
//      5 = bf16 PARTIAL out stride 512, no bias            [split-K gates]
//      6 = bf16 PARTIAL out stride 128, no bias            [split-K post]
// ---------------------------------------------------------------------------
template<int CA, int EPI>
DEVI void conv_body(const bf16* __restrict__ A, const bf16* __restrict__ Bt,
                    const float* __restrict__ bias, const float* __restrict__ bias2,
                    float* __restrict__ outF, bf16* __restrict__ outB,
                    const bf16* __restrict__ ST, const bf16* __restrict__ extra,
                    int s0, int s1, int m0, int n0,
                    bf16* AsBase, bf16* BsBase)
{
  constexpr int Kp = 25*CA;
  const int NS = s1 - s0;

  const int tid = threadIdx.x;
  const int wv = tid>>6, ln = tid&63;

  // staging: A 256x32 = 1024 chunks of 16B (thread t -> chunks t, t+512);
  // B 128x32 = 512. row = chunk>>2; phys chunk holds logical chunk^((row>>1)&3)
  // via pre-swizzled global source (0 LDS conflicts, measured r2-r9).
  const int rA = tid>>2;
  const int qs = ((tid&3) ^ ((rA>>1)&3))<<3;
  const int mA0 = m0 + rA, mA1 = m0 + 128 + rA;
  const long paA0 = ((long)(((mA0>>8)*20 + ((mA0>>4)&15))*20 + (mA0&15)))*CA + qs;
  const long paA1 = ((long)(((mA1>>8)*20 + ((mA1>>4)&15))*20 + (mA1&15)))*CA + qs;
  const long pbB  = (long)(n0 + rA)*Kp + qs;

  int kk0 = s0*32;
  int c0 = kk0 % CA;
  int tap = kk0 / CA;
  int kh = tap/5, kw = tap%5;
  int ks = kk0;

  auto stage = [&](int d){
    const long sh = (long)(kh*20 + kw)*CA + c0;
    char* la = (char*)AsBase + d*16384 + (wv<<10);
    char* lb = (char*)BsBase + d*8192  + (wv<<10);
    async16(A + paA0 + sh, la);
    async16(A + paA1 + sh, la + 8192);
    async16(Bt + pbB + ks, lb);
    ks += 32;
    c0 += 32; if (c0==CA){ c0=0; if(++kw==5){kw=0; ++kh;} }
  };

  f32x4 acc[4][4] = {};
  const int wm = wv>>1, wn = wv&1;
  const int rowA = (wm<<6) + (ln&15);
  const int rowB = (wn<<6) + (ln&15);
  const int kqA = (((ln>>4) ^ ((rowA>>1)&3))<<4);
  const int kqB = (((ln>>4) ^ ((rowB>>1)&3))<<4);

  stage(0); stage(1);
  int bc = 0, bs = 2;
  for (int t=0; t<NS; ++t) {
    if (t+1 < NS) waitbar<3>();
    else          waitbar<0>();
    if (t+2 < NS) stage(bs);

    const char* as_ = (const char*)AsBase + bc*16384;
    const char* bs_ = (const char*)BsBase + bc*8192;
    short8 af[4], bfr[4];
    #pragma unroll
    for (int mf=0; mf<4; mf++)
      af[mf] = *(const short8*)(as_ + ((rowA + (mf<<4))<<6) + kqA);
    #pragma unroll
    for (int nf=0; nf<4; nf++)
      bfr[nf] = *(const short8*)(bs_ + ((rowB + (nf<<4))<<6) + kqB);
    __builtin_amdgcn_s_setprio(1);
    #pragma unroll
    for (int mf=0; mf<4; mf++)
      #pragma unroll
      for (int nf=0; nf<4; nf++)
        acc[mf][nf] = __builtin_amdgcn_mfma_f32_16x16x32_bf16(af[mf], bfr[nf], acc[mf][nf], 0,0,0);
    __builtin_amdgcn_s_setprio(0);
    bc = (bc==2)?0:bc+1; bs = (bs==2)?0:bs+1;
  }

  const int mb = m0 + (wm<<6);
  const int nb = n0 + (wn<<6);
  const int ml = (ln>>4)<<2;
  const int nl = ln&15;
  #pragma unroll
  for (int mf=0; mf<4; mf++) {
    #pragma unroll
    for (int j=0; j<4; j++) {
      const int m = mb + (mf<<4) + ml + j;
      const long pI = pidx_(m);
      #pragma unroll
      for (int nf=0; nf<4; nf++) {
        const int n = nb + (nf<<4) + nl;
        const float v = acc[mf][nf][j];
        if constexpr (EPI==2) {
          if (n < 416) {
            float b  = (n < 394) ? bias[n] : 0.f;
            float st = __bfloat162float(ST[(long)m*416 + n]);
            float e  = (n < 128) ? __bfloat162float(extra[(pI<<7) + n]) : 0.f;
            outB[pI*416 + n] = __float2bfloat16(v + b + st + e);
          }
        } else if constexpr (EPI==4) {
          if (n < 352) {
            float b  = (n < 327) ? bias[n] : 0.f;
            float st = __bfloat162float(ST[(long)m*352 + n]);
            outB[pI*352 + n] = __float2bfloat16(v + b + st);
          } else if (n >= 384) {
            outF[((long)m<<7) + (n-384)] = v + bias2[n-384];
          }
        } else if constexpr (EPI==5) {  // split-K gates partial, stride 512
          outB[((long)m<<9) + n] = __float2bfloat16(v);
        } else {                        // EPI==6: split-K post partial, stride 128
          outB[((long)m<<7) + n] = __float2bfloat16(v);
        }
      }
    }
  }
}

// split-K=2 gates GEMM (r7 champion): grid (64,4,2); z = K-half -> same (m,n)
// tile pairs co-resident per CU (independent work fills barrier slack; shared
// A rows / B panel in L2). Partials summed (with bias) in lstm2_k.
template<int CA>
__global__ __launch_bounds__(512)
void conv_split(const bf16* __restrict__ A, const bf16* __restrict__ Bt,
                bf16* __restrict__ P0, bf16* __restrict__ P1)
{
  __shared__ alignas(16) bf16 As[3][256*32];
  __shared__ alignas(16) bf16 Bs[3][128*32];
  constexpr int NSUB = 25*CA/32;
  constexpr int H0 = NSUB - NSUB/2;
  const int z = blockIdx.z;
  conv_body<CA,5>(A, Bt, nullptr, nullptr, nullptr, z ? P1 : P0,
                  nullptr, nullptr, z ? H0 : 0, z ? NSUB : H0,
                  blockIdx.x<<8, blockIdx.y<<7, &As[0][0], &Bs[0][0]);
}

// merged decT+prior (z=0) and encT (z=1), 2 blocks/CU, PLUS fused wrc
// epilogue: canvas accumulate for the CURRENT hDec state (= h^t, the state
// wrc would have processed after the previous iteration's lstmD; h^0 is
// all-zero so its contribution is exactly 0). Wc read from global (24KB,
// L1-resident). Removes 7 serialized wrc dispatches from the critical path.
__global__ __launch_bounds__(512)
void conv_tp(const bf16* __restrict__ hDec, const bf16* __restrict__ BtDP,
             const float* __restrict__ dec_tb, const float* __restrict__ prior_b,
             float* __restrict__ PriorO, bf16* __restrict__ sDec,
             const bf16* __restrict__ STdec,
             const bf16* __restrict__ hEnc, const bf16* __restrict__ BtEncT,
             const float* __restrict__ enc_tb, bf16* __restrict__ sEnc,
             const bf16* __restrict__ STenc,
             const float* __restrict__ Wc, float* __restrict__ uc)
{
  __shared__ alignas(16) bf16 As[3][256*32];
  __shared__ alignas(16) bf16 Bs[3][128*32];
  const int m0 = blockIdx.x<<8, n0 = blockIdx.y<<7;
  if (blockIdx.z == 0)
    conv_body<128,4>(hDec, BtDP, dec_tb, prior_b, PriorO, sDec, STdec, nullptr,
                     0, 100, m0, n0, &As[0][0], &Bs[0][0]);
  else
    conv_body<128,2>(hEnc, BtEncT, enc_tb, nullptr, nullptr, sEnc, STenc, hDec,
                     0, 100, m0, n0, &As[0][0], &Bs[0][0]);

  // wrc epilogue: 512 blocks x 32 m-rows each covers MTOT exactly.
  const int gid = blockIdx.z*256 + blockIdx.y*64 + blockIdx.x;
  const int tid = threadIdx.x;
  const int m = (gid<<5) + (tid>>4);
  const int pix = tid&15;
  const int nb = m>>8, iy=(m>>4)&15, ix=m&15;
  const bf16* __restrict__ h = hDec + (pidx_(m)<<7);
  float a0=0.f, a1=0.f, a2=0.f;
  #pragma unroll 4
  for (int c=0;c<128;c++) {
    float hv = __bfloat162float(h[c]);
    const float* wl = Wc + c*48 + pix*3;
    a0 += hv*wl[0]; a1 += hv*wl[1]; a2 += hv*wl[2];
  }
  const int ki = pix>>2, kj = pix&3;
  long ob = ((long)((nb<<6) + (iy<<2) + ki)*64 + (ix<<2) + kj)*3;
  uc[ob+0] += a0; uc[ob+1] += a1; uc[ob+2] += a2;
}

// post GEMM split-K=4: grid (64,1,4); partial planes of 16384x128 bf16.
__global__ __launch_bounds__(512)
void conv_post(const bf16* __restrict__ hEnc, const bf16* __restrict__ BtPost,
               bf16* __restrict__ PP)
{
  __shared__ alignas(16) bf16 As[3][256*32];
  __shared__ alignas(16) bf16 Bs[3][128*32];
  const int z = blockIdx.z;
  conv_body<128,6>(hEnc, BtPost, nullptr, nullptr, nullptr,
                   PP + (long)z*MTOT*128, nullptr, nullptr,
                   z*25, z*25+25, blockIdx.x<<8, 0, &As[0][0], &Bs[0][0]);
}

// OIHW f32 -> Bt[n=o][k=(kh*5+kw)*CA + c] bf16, rows o>=O and cols c>=I zeroed.
__global__ void repack_w_k(const float* __restrict__ w, bf16* __restrict__ Bt,
                           int O, int I, int CA, long total)
{
  long e = (long)blockIdx.x*256 + threadIdx.x;
  if (e >= total) return;
  const int Kp = 25*CA;
  int o = (int)(e / Kp);
  int k = (int)(e % Kp);
  int blk = k / CA, c = k % CA;
  int kh = blk / 5, kwi = blk % 5;
  float v = 0.f;
  if (o < O && c < I) v = w[((long)o*I + c)*25 + kh*5 + kwi];
  Bt[e] = __float2bfloat16(v);
}

// Wcomb[c][pix*3+o] = sum_m write_w[c,m,ki,kj] * obs_w[o,m]   (pix = ki*4+kj)
__global__ void wcomb_k(const float* __restrict__ ww, const float* __restrict__ ow,
                        float* __restrict__ Wc)
{
  int idx = blockIdx.x*256 + threadIdx.x;
  if (idx >= 128*48) return;
  int c = idx / 48, rst = idx % 48;
  int pix = rst / 3, o = rst % 3;
  int ki = pix >> 2, kj = pix & 3;
  float a = 0.f;
  for (int mm=0; mm<128; mm++)
    a += ww[(((long)c*128 + mm)*4 + ki)*4 + kj] * ow[o*128 + mm];
  Wc[idx] = a;
}

// xr = conv(x, read_w, stride 4), xr[m*3+o]
__global__ void xr_k(const float* __restrict__ x, const float* __restrict__ rw,
                     float* __restrict__ xr)
{
  int idx = blockIdx.x*256 + threadIdx.x;
  if (idx >= MTOT*3) return;
  int m = idx / 3, o = idx % 3;
  int nb = m>>8, iy=(m>>4)&15, ix=m&15;
  float a = 0.f;
  for (int c=0;c<3;c++)
    for (int kh=0;kh<4;kh++)
      for (int kw=0;kw<4;kw++)
        a += x[((long)(nb*3+c)*64 + (iy*4+kh))*64 + (ix*4+kw)] * rw[((o*3+c)*4+kh)*4+kw];
  xr[idx] = a;
}

// static concat part for enc: channels 128..393 of ST_enc (stride 416)
__global__ void st_enc_k(const float* __restrict__ xr, const float* __restrict__ v,
                         const float* __restrict__ r, bf16* __restrict__ ST)
{
  long g = (long)blockIdx.x*256 + threadIdx.x;
  if (g >= (long)MTOT*266) return;
  int m = (int)(g / 266), ch = (int)(g % 266);
  int nb = m>>8, sp = m&255;
  float val;
  if (ch < 3)       val = xr[m*3 + ch];
  else if (ch < 10) val = v[nb*7 + ch - 3];
  else              val = r[((long)nb*256 + (ch-10))*256 + sp];
  ST[(long)m*416 + 128 + ch] = __float2bfloat16(val);
}

// static concat part for dec: channels 64..326 of ST_dec (stride 352)
__global__ void st_dec_k(const float* __restrict__ v, const float* __restrict__ r,
                         bf16* __restrict__ ST)
{
  long g = (long)blockIdx.x*256 + threadIdx.x;
  if (g >= (long)MTOT*263) return;
  int m = (int)(g / 263), ch = (int)(g % 263);
  int nb = m>>8, sp = m&255;
  float val;
  if (ch < 7) val = v[nb*7 + ch];
  else        val = r[((long)nb*256 + (ch-7))*256 + sp];
  ST[(long)m*352 + 64 + ch] = __float2bfloat16(val);
}

// LSTM pointwise over split-K=2 partials: gates = P0+P1+bias (f,i,o,s)
__global__ void lstm2_k(const bf16* __restrict__ P0, const bf16* __restrict__ P1,
                        const float* __restrict__ gb_, float* __restrict__ cbuf,
                        bf16* __restrict__ hpad)
{
  int idx = blockIdx.x*256 + threadIdx.x;   // exactly MTOT*128
  int m = idx >> 7, c = idx & 127;
  long gb = (long)m << 9;
  float f = __bfloat162float(P0[gb + c])       + __bfloat162float(P1[gb + c])       + gb_[c];
  float i = __bfloat162float(P0[gb + 128 + c]) + __bfloat162float(P1[gb + 128 + c]) + gb_[128 + c];
  float o = __bfloat162float(P0[gb + 256 + c]) + __bfloat162float(P1[gb + 256 + c]) + gb_[256 + c];
  float s = __bfloat162float(P0[gb + 384 + c]) + __bfloat162float(P1[gb + 384 + c]) + gb_[384 + c];
  float cell = sigm_(f)*cbuf[idx] + sigm_(i)*tanhf(s);
  cbuf[idx] = cell;
  hpad[(pidx_(m)<<7) + c] = __float2bfloat16(sigm_(o)*tanhf(cell));
}

// z = q_mu + exp(0.5 q_lv)*eps with q = sum of 4 post partials + bias;
// ADD z into sDec ch 0..63 ; KL partial per block (no contended atomics)
__global__ void zkl4_k(const bf16* __restrict__ PP, const float* __restrict__ pb,
                       const float* __restrict__ prior, const float* __restrict__ eps_t,
                       bf16* __restrict__ sDec, float* __restrict__ part)
{
  __shared__ float wsum[4];
  const long PL = (long)MTOT*128;
  int idx = blockIdx.x*256 + threadIdx.x;   // exactly MTOT*64
  int m = idx >> 6, c = idx & 63;
  float qm = pb[c], ql = pb[64 + c];
  #pragma unroll
  for (int z=0; z<4; ++z) {
    qm += __bfloat162float(PP[z*PL + ((long)m<<7) + c]);
    ql += __bfloat162float(PP[z*PL + ((long)m<<7) + 64 + c]);
  }
  long pbx = (long)m << 7;
  float pm = prior[pbx + c], pl = prior[pbx + 64 + c];
  int nb = m>>8, sp = m&255;
  float e = eps_t[((long)nb*64 + c)*256 + sp];
  float z = qm + expf(0.5f*ql)*e;
  long so = pidx_(m)*352 + c;
  sDec[so] = __float2bfloat16(__bfloat162float(sDec[so]) + z);
  float kl = expf(ql - pl) + (pm-qm)*(pm-qm)*expf(-pl) - 1.f + (pl - ql);
  #pragma unroll
  for (int off=32; off>0; off>>=1) kl += __shfl_down(kl, off);
  if ((threadIdx.x & 63) == 0) wsum[threadIdx.x >> 6] = kl;
  __syncthreads();
  if (threadIdx.x == 0)
    part[blockIdx.x] = wsum[0] + wsum[1] + wsum[2] + wsum[3];
}

// standalone canvas accumulate (used once, for the final hDec state h^8)
__global__ __launch_bounds__(256)
void wrc_k(const bf16* __restrict__ hpad, const float* __restrict__ Wc,
           float* __restrict__ uc)
{
  __shared__ float Wl[128*48];
  for (int i = threadIdx.x; i < 128*48; i += 256) Wl[i] = Wc[i];
  __syncthreads();
  int t = threadIdx.x;
  int mloc = t >> 4, pix = t & 15;
  int m = (blockIdx.x<<4) + mloc;
  int nb = m>>8, iy=(m>>4)&15, ix=m&15;
  const bf16* h = hpad + (pidx_(m)<<7);
  float a0=0.f, a1=0.f, a2=0.f;
  for (int c=0;c<128;c++) {
    float hv = __bfloat162float(h[c]);
    const float* wl = Wl + c*48 + pix*3;
    a0 += hv*wl[0]; a1 += hv*wl[1]; a2 += hv*wl[2];
  }
  int ki = pix>>2, kj = pix&3;
  long ob = ((long)((nb<<6) + (iy<<2) + ki)*64 + (ix<<2) + kj)*3;
  uc[ob+0] += a0; uc[ob+1] += a1; uc[ob+2] += a2;
}

__global__ void canvas_k(const float* __restrict__ uc, const float* __restrict__ ob,
                         float* __restrict__ out)
{
  int idx = blockIdx.x*256 + threadIdx.x;   // exactly 786432, NCHW order
  int x = idx & 63, y = (idx>>6)&63;
  int rem = idx >> 12;
  int o = rem % 3, n = rem / 3;
  float v = uc[((long)((n<<6)+y)*64 + x)*3 + o] + ob[o];
  out[idx] = 1.f/(1.f+expf(-v));
}

// final KL: sum 8*4096 per-block partials, scale, write out[786432]
__global__ void klred_k(const float* __restrict__ part, float* __restrict__ out)
{
  __shared__ float wsum[4];
  float a = 0.f;
  for (int i = threadIdx.x; i < 32768; i += 256) a += part[i];
  #pragma unroll
  for (int off=32; off>0; off>>=1) a += __shfl_down(a, off);
  if ((threadIdx.x & 63) == 0) wsum[threadIdx.x >> 6] = a;
  __syncthreads();
  if (threadIdx.x == 0)
    out[786432] = (wsum[0] + wsum[1] + wsum[2] + wsum[3]) * (0.5f/64.f);
}

// ---------------------------------------------------------------------------
// workspace layout (bytes). P0/P1 gate partial planes; PostP (4 x 4.2MB)
// ALIASES P0 — lifetimes disjoint within an iteration.
static const long O_BT_POST  = 0;                     // 128*3200*2
static const long O_BT_ENCT  = O_BT_POST  + 819200;   // 512*3200*2
static const long O_BT_DP    = O_BT_ENCT  + 3276800;  // 512*3200*2
static const long O_BT_ENCG  = O_BT_DP    + 3276800;  // 512*10400*2
static const long O_BT_DECG  = O_BT_ENCG  + 10649600; // 512*8800*2
static const long O_WCOMB    = O_BT_DECG  + 9011200;  // 6144*4
static const long O_XR       = O_WCOMB    + 24576;    // 49152*4
static const long O_KLP      = O_XR       + 196608;   // 32768*4
static const long O_STENC    = O_KLP      + 131072;   // 16384*416*2
static const long O_STDEC    = O_STENC    + 13631488; // 16384*352*2
static const long O_HENC     = O_STDEC    + 11534336; // 25600*128*2
static const long O_HDEC     = O_HENC     + 6553600;
static const long O_SENC     = O_HDEC     + 6553600;  // 25600*416*2
static const long O_SDEC     = O_SENC     + 21299200; // 25600*352*2
static const long O_CENC     = O_SDEC     + 18022400; // 16384*128*4
static const long O_CDEC     = O_CENC     + 8388608;
static const long O_PRIOR    = O_CDEC     + 8388608;  // 16384*128*4
static const long O_PG       = O_PRIOR    + 8388608;  // 2 x 16777216
static const long O_UC       = O_PG       + 33554432; // 786432*4
static const long WS_TOTAL   = O_UC       + 3145728;  // ~167 MB

extern "C" void kernel_launch(void* const* d_in, const int* in_sizes, int n_in,
                              void* d_out, int out_size, void* d_ws, size_t ws_size,
                              hipStream_t stream)
{
  const float* x       = (const float*)d_in[0];
  const float* v       = (const float*)d_in[1];
  const float* r       = (const float*)d_in[2];
  const float* eps     = (const float*)d_in[3];
  const float* read_w  = (const float*)d_in[4];
  const float* write_w = (const float*)d_in[5];
  const float* prior_w = (const float*)d_in[6];
  const float* prior_b = (const float*)d_in[7];
  const float* post_w  = (const float*)d_in[8];
  const float* post_b  = (const float*)d_in[9];
  const float* enc_gw  = (const float*)d_in[10];
  const float* enc_gb  = (const float*)d_in[11];
  const float* enc_tw  = (const float*)d_in[12];
  const float* enc_tb  = (const float*)d_in[13];
  const float* dec_gw  = (const float*)d_in[14];
  const float* dec_gb  = (const float*)d_in[15];
  const float* dec_tw  = (const float*)d_in[16];
  const float* dec_tb  = (const float*)d_in[17];
  const float* obs_w   = (const float*)d_in[18];
  const float* obs_b   = (const float*)d_in[19];

  char* ws = (char*)d_ws;
  bf16* BtPost  = (bf16*)(ws + O_BT_POST);
  bf16* BtEncT  = (bf16*)(ws + O_BT_ENCT);
  bf16* BtDP    = (bf16*)(ws + O_BT_DP);
  bf16* BtEncG  = (bf16*)(ws + O_BT_ENCG);
  bf16* BtDecG  = (bf16*)(ws + O_BT_DECG);
  float* Wcomb  = (float*)(ws + O_WCOMB);
  float* XR     = (float*)(ws + O_XR);
  float* KLpart = (float*)(ws + O_KLP);
  bf16* STenc   = (bf16*)(ws + O_STENC);
  bf16* STdec   = (bf16*)(ws + O_STDEC);
  bf16* hEnc    = (bf16*)(ws + O_HENC);
  bf16* hDec    = (bf16*)(ws + O_HDEC);
  bf16* sEnc    = (bf16*)(ws + O_SENC);
  bf16* sDec    = (bf16*)(ws + O_SDEC);
  float* cEnc   = (float*)(ws + O_CENC);
  float* cDec   = (float*)(ws + O_CDEC);
  float* PriorO = (float*)(ws + O_PRIOR);
  bf16* P0      = (bf16*)(ws + O_PG);
  bf16* P1      = (bf16*)(ws + O_PG + 16777216);
  bf16* PostP   = (bf16*)(ws + O_PG);            // aliases P0 (disjoint lifetime)
  float* Ucomb  = (float*)(ws + O_UC);
  float* out    = (float*)d_out;

  size_t clr = (size_t)WS_TOTAL; if (clr > ws_size) clr = ws_size;
  hipMemsetAsync(d_ws, 0, clr, stream);

  // weight repacks
  repack_w_k<<<1600, 256, 0, stream>>>(post_w,  BtPost, 128, 128, 128, 128L*3200);
  repack_w_k<<<6400, 256, 0, stream>>>(enc_tw,  BtEncT, 394, 128, 128, 512L*3200);
  repack_w_k<<<4800, 256, 0, stream>>>(dec_tw,  BtDP,   327, 128, 128, 384L*3200);
  repack_w_k<<<1600, 256, 0, stream>>>(prior_w, BtDP + 384L*3200, 128, 128, 128, 128L*3200);
  repack_w_k<<<20800,256, 0, stream>>>(enc_gw,  BtEncG, 512, 394, 416, 512L*10400);
  repack_w_k<<<17600,256, 0, stream>>>(dec_gw,  BtDecG, 512, 327, 352, 512L*8800);
  wcomb_k<<<24, 256, 0, stream>>>(write_w, obs_w, Wcomb);
  xr_k<<<192, 256, 0, stream>>>(x, read_w, XR);
  st_enc_k<<<(int)(((long)MTOT*266 + 255)/256), 256, 0, stream>>>(XR, v, r, STenc);
  st_dec_k<<<(int)(((long)MTOT*263 + 255)/256), 256, 0, stream>>>(v, r, STdec);

  for (int t = 0; t < 8; ++t) {
    // merged: z=0 sDec=decT(hDec)+tb+ST & PriorO ; z=1 sEnc=encT(hEnc)+tb+ST+hDec
    // + fused wrc epilogue on current hDec (h^t; h^0 is zero -> contributes 0)
    conv_tp<<<dim3(64,4,2), 512, 0, stream>>>(
        hDec, BtDP, dec_tb, prior_b, PriorO, sDec, STdec,
        hEnc, BtEncT, enc_tb, sEnc, STenc, Wcomb, Ucomb);
    // enc gates: split-K=2, 2 blocks/CU (r7 champion)
    conv_split<416><<<dim3(64,4,2), 512, 0, stream>>>(sEnc, BtEncG, P0, P1);
    lstm2_k<<<8192, 256, 0, stream>>>(P0, P1, enc_gb, cEnc, hEnc);
    // post split-K=4 -> partial planes (alias of P0; gates planes dead now)
    conv_post<<<dim3(64,1,4), 512, 0, stream>>>(hEnc, BtPost, PostP);
    // z (sum partials + bias) -> add into sDec ch0..63 ; KL partials
    zkl4_k<<<4096, 256, 0, stream>>>(PostP, post_b, PriorO,
                                     eps + (long)t*64*64*256, sDec,
                                     KLpart + (long)t*4096);
    // dec gates: split-K=2
    conv_split<352><<<dim3(64,4,2), 512, 0, stream>>>(sDec, BtDecG, P0, P1);
    lstm2_k<<<8192, 256, 0, stream>>>(P0, P1, dec_gb, cDec, hDec);
  }

  // final canvas contribution from h^8 (the loop's epilogues covered h^1..h^7)
  wrc_k<<<1024, 256, 0, stream>>>(hDec, Wcomb, Ucomb);
  canvas_k<<<3072, 256, 0, stream>>>(Ucomb, obs_b, out);
  klred_k<<<1, 256, 0, stream>>>(KLpart, out);
}

// Round 11
// 2862.328 us; speedup vs baseline: 1.4626x; 1.3905x over previous
//
#include <hip/hip_runtime.h>
#include <hip/hip_bf16.h>

using bf16 = __hip_bfloat16;
typedef __attribute__((ext_vector_type(8))) short short8;
typedef __attribute__((ext_vector_type(4))) float f32x4;
typedef __attribute__((ext_vector_type(8))) int i32x8;
typedef __attribute__((ext_vector_type(4))) int i32x4;

#define DEVI __device__ __forceinline__

#define MTOT 16384      // 64 * 16 * 16 output positions
#define PADS 25600      // 64 * 20 * 20 padded positions

DEVI float sigm_(float x){ return 1.f/(1.f+expf(-x)); }

DEVI long pidx_(int m){
  int nb = m>>8, iy=(m>>4)&15, ix=m&15;
  return (long)(nb*20 + iy + 2)*20 + (ix + 2);
}

DEVI unsigned char f2fp8(float x){
  int p = __builtin_amdgcn_cvt_pk_fp8_f32(x, 0.f, 0, false);
  return (unsigned char)(p & 0xFF);
}
DEVI float fp82f(unsigned char v){
  return __builtin_amdgcn_cvt_f32_fp8((int)v, 0);
}

// async global->LDS, 16B per lane. LDS dest = wave-uniform base + lane*16.
DEVI void async16(const void* g, void* l) {
  __builtin_amdgcn_global_load_lds(
      (__attribute__((address_space(1))) void*)(unsigned long long)g,
      (__attribute__((address_space(3))) void*)(unsigned int)(unsigned long long)l,
      16, 0, 0);
}

template<int N> DEVI void waitbar(){
  if constexpr (N==0)      asm volatile("s_waitcnt vmcnt(0)\ns_barrier" ::: "memory");
  else if constexpr (N==3) asm volatile("s_waitcnt vmcnt(3)\ns_barrier" ::: "memory");
  else                     asm volatile("s_waitcnt vmcnt(6)\ns_barrier" ::: "memory");
}

// ---------------------------------------------------------------------------
// MX-fp8 gates GEMM. BM=128, BN=128, BK=128 (one mfma_scale per frag-K),
// 4 waves 2Mx2N (wave 64x64, 4x4 frags), double-buffered 64KB LDS -> 2
// blocks/CU. A8: padded NHWC fp8 [PADS][CA]. Bt8: [512][NS*128] fp8, weights
// pre-scaled x32; scale_b = 122 (2^-5) undoes it exactly; scale_a = 127.
// Rows are 128B; swizzle chunk ^= (row&7) via pre-swizzled source (each
// 8-lane batch of a b128 read covers all 8 bank-groups -> conflict-free).
// Stage-after-barrier + vmcnt(0): load is in flight one full ~1300cy phase
// (>> 900cy HBM) before its wait. K padded to NS*128 with zero B rows
// (A over-reads stay inside d_ws; x0 contribution).
// Output: bf16 gates stride 512, + bias (no split-K).
// ---------------------------------------------------------------------------
template<int CA, int NS>
__global__ __launch_bounds__(256)
void conv_g8(const unsigned char* __restrict__ A8,
             const unsigned char* __restrict__ Bt8,
             const float* __restrict__ bias, bf16* __restrict__ outB)
{
  constexpr int Kp8 = NS*128;
  __shared__ alignas(16) unsigned char As[2][16384];
  __shared__ alignas(16) unsigned char Bs[2][16384];

  const int m0 = blockIdx.x<<7;
  const int n0 = blockIdx.y<<7;
  const int tid = threadIdx.x;
  const int wv = tid>>6, ln = tid&63;

  // staging: A/B tiles 128 rows x 8 chunks of 16B = 1024 pieces each;
  // thread t -> pieces t+256i (row rr+32i, phys chunk t&7). logical chunk
  // lc = (t&7)^(rr&7); LDS dest byte = (t+256i)*16 = t*16 + i*4096 (linear).
  const int rr = tid>>3;
  const int lc = (tid&7) ^ (rr&7);
  long paRC[4], pbR[4];
  #pragma unroll
  for (int i=0;i<4;i++){
    int m = m0 + rr + (i<<5);
    paRC[i] = (long)(((m>>8)*20 + ((m>>4)&15))*20 + (m&15)) * CA;
    pbR[i]  = (long)(n0 + rr + (i<<5))*Kp8 + lc*16;
  }

  int cc = lc*16, tp = 0, ks = 0;
  auto stage = [&](int d){
    const int shiftC = ((tp/5)*20 + (tp%5)) * CA;
    char* la = (char*)&As[d][0] + (wv<<10);
    char* lb = (char*)&Bs[d][0] + (wv<<10);
    #pragma unroll
    for (int i=0;i<4;i++) async16(A8 + paRC[i] + shiftC + cc, la + i*4096);
    #pragma unroll
    for (int i=0;i<4;i++) async16(Bt8 + pbR[i] + ks, lb + i*4096);
    cc += 128; if (cc >= CA){ cc -= CA; tp++; }
    ks += 128;
  };

  f32x4 acc[4][4] = {};
  const int wm = wv>>1, wn = wv&1;
  const int rA0 = (wm<<6) + (ln&15);
  const int rB0 = (wn<<6) + (ln&15);
  const int xa = ln&7;                 // row&7, invariant across +16*f
  const int q2 = (ln>>4)<<1;           // 32B = logical chunks {2q, 2q+1}
  const int c0 = ((q2    ) ^ xa)<<4;
  const int c1 = ((q2 | 1) ^ xa)<<4;

  stage(0);
  for (int t=0; t<NS; ++t) {
    asm volatile("s_waitcnt vmcnt(0)\ns_barrier" ::: "memory");
    if (t+1 < NS) stage((t+1)&1);      // overwrites buffer released at barrier

    const char* as_ = (const char*)&As[t&1][0];
    const char* bs_ = (const char*)&Bs[t&1][0];
    i32x8 af[4], bfr[4];
    #pragma unroll
    for (int f=0; f<4; f++){
      const char* p = as_ + ((rA0 + (f<<4))<<7);
      ((i32x4*)&af[f])[0] = *(const i32x4*)(p + c0);
      ((i32x4*)&af[f])[1] = *(const i32x4*)(p + c1);
    }
    #pragma unroll
    for (int f=0; f<4; f++){
      const char* p = bs_ + ((rB0 + (f<<4))<<7);
      ((i32x4*)&bfr[f])[0] = *(const i32x4*)(p + c0);
      ((i32x4*)&bfr[f])[1] = *(const i32x4*)(p + c1);
    }
    __builtin_amdgcn_s_setprio(1);
    #pragma unroll
    for (int mf=0; mf<4; mf++)
      #pragma unroll
      for (int nf=0; nf<4; nf++)
        acc[mf][nf] = __builtin_amdgcn_mfma_scale_f32_16x16x128_f8f6f4(
            af[mf], bfr[nf], acc[mf][nf], 0, 0, 0, 127, 0, 122);
    __builtin_amdgcn_s_setprio(0);
  }

  const int mb = m0 + (wm<<6);
  const int nb = n0 + (wn<<6);
  const int ml = (ln>>4)<<2;
  const int nl = ln&15;
  #pragma unroll
  for (int mf=0; mf<4; mf++) {
    #pragma unroll
    for (int j=0; j<4; j++) {
      const int m = mb + (mf<<4) + ml + j;
      #pragma unroll
      for (int nf=0; nf<4; nf++) {
        const int n = nb + (nf<<4) + nl;
        outB[((long)m<<9) + n] = __float2bfloat16(acc[mf][nf][j] + bias[n]);
      }
    }
  }
}

// ---------------------------------------------------------------------------
// r7-proven 8-wave bf16 conv body (BM=256, BN=128, BK=32, triple-buffer,
// depth-2, counted vmcnt(3), setprio). Used by conv_tp / conv_post.
// EPI: 2 = s_enc FP8 padded stride 416, +b(n<394) +ST +h_dec(n<128)
//      4 = fused decT+prior: n<352 -> sDec8 fp8 (+b(n<327)+ST); n>=384 prior f32
//      6 = bf16 PARTIAL out stride 128, no bias            [split-K post]
// ---------------------------------------------------------------------------
template<int CA, int EPI>
DEVI void conv_body(const bf16* __restrict__ A, const bf16* __restrict__ Bt,
                    const float* __restrict__ bias, const float* __restrict__ bias2,
                    float* __restrict__ outF, bf16* __restrict__ outB,
                    unsigned char* __restrict__ out8,
                    const bf16* __restrict__ ST, const bf16* __restrict__ extra,
                    int s0, int s1, int m0, int n0,
                    bf16* AsBase, bf16* BsBase)
{
  constexpr int Kp = 25*CA;
  const int NS = s1 - s0;

  const int tid = threadIdx.x;
  const int wv = tid>>6, ln = tid&63;

  const int rA = tid>>2;
  const int qs = ((tid&3) ^ ((rA>>1)&3))<<3;
  const int mA0 = m0 + rA, mA1 = m0 + 128 + rA;
  const long paA0 = ((long)(((mA0>>8)*20 + ((mA0>>4)&15))*20 + (mA0&15)))*CA + qs;
  const long paA1 = ((long)(((mA1>>8)*20 + ((mA1>>4)&15))*20 + (mA1&15)))*CA + qs;
  const long pbB  = (long)(n0 + rA)*Kp + qs;

  int kk0 = s0*32;
  int c0 = kk0 % CA;
  int tap = kk0 / CA;
  int kh = tap/5, kw = tap%5;
  int ks = kk0;

  auto stage = [&](int d){
    const long sh = (long)(kh*20 + kw)*CA + c0;
    char* la = (char*)AsBase + d*16384 + (wv<<10);
    char* lb = (char*)BsBase + d*8192  + (wv<<10);
    async16(A + paA0 + sh, la);
    async16(A + paA1 + sh, la + 8192);
    async16(Bt + pbB + ks, lb);
    ks += 32;
    c0 += 32; if (c0==CA){ c0=0; if(++kw==5){kw=0; ++kh;} }
  };

  f32x4 acc[4][4] = {};
  const int wm = wv>>1, wn = wv&1;
  const int rowA = (wm<<6) + (ln&15);
  const int rowB = (wn<<6) + (ln&15);
  const int kqA = (((ln>>4) ^ ((rowA>>1)&3))<<4);
  const int kqB = (((ln>>4) ^ ((rowB>>1)&3))<<4);

  stage(0); stage(1);
  int bc = 0, bs = 2;
  for (int t=0; t<NS; ++t) {
    if (t+1 < NS) waitbar<3>();
    else          waitbar<0>();
    if (t+2 < NS) stage(bs);

    const char* as_ = (const char*)AsBase + bc*16384;
    const char* bs_ = (const char*)BsBase + bc*8192;
    short8 af[4], bfr[4];
    #pragma unroll
    for (int mf=0; mf<4; mf++)
      af[mf] = *(const short8*)(as_ + ((rowA + (mf<<4))<<6) + kqA);
    #pragma unroll
    for (int nf=0; nf<4; nf++)
      bfr[nf] = *(const short8*)(bs_ + ((rowB + (nf<<4))<<6) + kqB);
    __builtin_amdgcn_s_setprio(1);
    #pragma unroll
    for (int mf=0; mf<4; mf++)
      #pragma unroll
      for (int nf=0; nf<4; nf++)
        acc[mf][nf] = __builtin_amdgcn_mfma_f32_16x16x32_bf16(af[mf], bfr[nf], acc[mf][nf], 0,0,0);
    __builtin_amdgcn_s_setprio(0);
    bc = (bc==2)?0:bc+1; bs = (bs==2)?0:bs+1;
  }

  const int mb = m0 + (wm<<6);
  const int nb = n0 + (wn<<6);
  const int ml = (ln>>4)<<2;
  const int nl = ln&15;
  #pragma unroll
  for (int mf=0; mf<4; mf++) {
    #pragma unroll
    for (int j=0; j<4; j++) {
      const int m = mb + (mf<<4) + ml + j;
      const long pI = pidx_(m);
      #pragma unroll
      for (int nf=0; nf<4; nf++) {
        const int n = nb + (nf<<4) + nl;
        const float v = acc[mf][nf][j];
        if constexpr (EPI==2) {
          if (n < 416) {
            float b  = (n < 394) ? bias[n] : 0.f;
            float st = __bfloat162float(ST[(long)m*416 + n]);
            float e  = (n < 128) ? __bfloat162float(extra[(pI<<7) + n]) : 0.f;
            out8[pI*416 + n] = f2fp8(v + b + st + e);
          }
        } else if constexpr (EPI==4) {
          if (n < 352) {
            float b  = (n < 327) ? bias[n] : 0.f;
            float st = __bfloat162float(ST[(long)m*352 + n]);
            out8[pI*352 + n] = f2fp8(v + b + st);
          } else if (n >= 384) {
            outF[((long)m<<7) + (n-384)] = v + bias2[n-384];
          }
        } else { // EPI==6: split-K post partial, stride 128, no bias
          outB[((long)m<<7) + n] = __float2bfloat16(v);
        }
      }
    }
  }
}

// merged decT+prior (z=0) and encT (z=1), 2 blocks/CU, + fused wrc epilogue
// on the current hDec (h^t; h^0 zero -> contributes 0).
__global__ __launch_bounds__(512)
void conv_tp(const bf16* __restrict__ hDec, const bf16* __restrict__ BtDP,
             const float* __restrict__ dec_tb, const float* __restrict__ prior_b,
             float* __restrict__ PriorO, unsigned char* __restrict__ sDec8,
             const bf16* __restrict__ STdec,
             const bf16* __restrict__ hEnc, const bf16* __restrict__ BtEncT,
             const float* __restrict__ enc_tb, unsigned char* __restrict__ sEnc8,
             const bf16* __restrict__ STenc,
             const float* __restrict__ Wc, float* __restrict__ uc)
{
  __shared__ alignas(16) bf16 As[3][256*32];
  __shared__ alignas(16) bf16 Bs[3][128*32];
  const int m0 = blockIdx.x<<8, n0 = blockIdx.y<<7;
  if (blockIdx.z == 0)
    conv_body<128,4>(hDec, BtDP, dec_tb, prior_b, PriorO, nullptr, sDec8,
                     STdec, nullptr, 0, 100, m0, n0, &As[0][0], &Bs[0][0]);
  else
    conv_body<128,2>(hEnc, BtEncT, enc_tb, nullptr, nullptr, nullptr, sEnc8,
                     STenc, hDec, 0, 100, m0, n0, &As[0][0], &Bs[0][0]);

  // wrc epilogue: 512 blocks x 32 m-rows covers MTOT exactly.
  const int gid = blockIdx.z*256 + blockIdx.y*64 + blockIdx.x;
  const int tid = threadIdx.x;
  const int m = (gid<<5) + (tid>>4);
  const int pix = tid&15;
  const int nb = m>>8, iy=(m>>4)&15, ix=m&15;
  const bf16* __restrict__ h = hDec + (pidx_(m)<<7);
  float a0=0.f, a1=0.f, a2=0.f;
  #pragma unroll 4
  for (int c=0;c<128;c++) {
    float hv = __bfloat162float(h[c]);
    const float* wl = Wc + c*48 + pix*3;
    a0 += hv*wl[0]; a1 += hv*wl[1]; a2 += hv*wl[2];
  }
  const int ki = pix>>2, kj = pix&3;
  long ob = ((long)((nb<<6) + (iy<<2) + ki)*64 + (ix<<2) + kj)*3;
  uc[ob+0] += a0; uc[ob+1] += a1; uc[ob+2] += a2;
}

// post GEMM split-K=4: grid (64,1,4); partial planes of 16384x128 bf16.
__global__ __launch_bounds__(512)
void conv_post(const bf16* __restrict__ hEnc, const bf16* __restrict__ BtPost,
               bf16* __restrict__ PP)
{
  __shared__ alignas(16) bf16 As[3][256*32];
  __shared__ alignas(16) bf16 Bs[3][128*32];
  const int z = blockIdx.z;
  conv_body<128,6>(hEnc, BtPost, nullptr, nullptr, nullptr,
                   PP + (long)z*MTOT*128, nullptr, nullptr, nullptr,
                   z*25, z*25+25, blockIdx.x<<8, 0, &As[0][0], &Bs[0][0]);
}

// OIHW f32 -> Bt[n=o][k=(kh*5+kw)*CA + c] bf16, rows o>=O / cols c>=I zeroed.
__global__ void repack_w_k(const float* __restrict__ w, bf16* __restrict__ Bt,
                           int O, int I, int CA, long total)
{
  long e = (long)blockIdx.x*256 + threadIdx.x;
  if (e >= total) return;
  const int Kp = 25*CA;
  int o = (int)(e / Kp);
  int k = (int)(e % Kp);
  int blk = k / CA, c = k % CA;
  float v = 0.f;
  if (o < O && c < I) v = w[((long)o*I + c)*25 + blk];
  Bt[e] = __float2bfloat16(v);
}

// fp8 repack with x32 scale (undone by MFMA scale_b = 2^-5) and K padded
// to Kp8 = NS*128 (zero rows beyond 25*CA).
__global__ void repack_w8_k(const float* __restrict__ w, unsigned char* __restrict__ Bt,
                            int O, int I, int CA, int Kp8, long total)
{
  long e = (long)blockIdx.x*256 + threadIdx.x;
  if (e >= total) return;
  int o = (int)(e / Kp8);
  int k = (int)(e % Kp8);
  float v = 0.f;
  if (k < 25*CA) {
    int blk = k / CA, c = k % CA;
    if (o < O && c < I) v = w[((long)o*I + c)*25 + blk] * 32.0f;
  }
  Bt[e] = f2fp8(v);
}

// Wcomb[c][pix*3+o] = sum_m write_w[c,m,ki,kj] * obs_w[o,m]   (pix = ki*4+kj)
__global__ void wcomb_k(const float* __restrict__ ww, const float* __restrict__ ow,
                        float* __restrict__ Wc)
{
  int idx = blockIdx.x*256 + threadIdx.x;
  if (idx >= 128*48) return;
  int c = idx / 48, rst = idx % 48;
  int pix = rst / 3, o = rst % 3;
  int ki = pix >> 2, kj = pix & 3;
  float a = 0.f;
  for (int mm=0; mm<128; mm++)
    a += ww[(((long)c*128 + mm)*4 + ki)*4 + kj] * ow[o*128 + mm];
  Wc[idx] = a;
}

// xr = conv(x, read_w, stride 4), xr[m*3+o]
__global__ void xr_k(const float* __restrict__ x, const float* __restrict__ rw,
                     float* __restrict__ xr)
{
  int idx = blockIdx.x*256 + threadIdx.x;
  if (idx >= MTOT*3) return;
  int m = idx / 3, o = idx % 3;
  int nb = m>>8, iy=(m>>4)&15, ix=m&15;
  float a = 0.f;
  for (int c=0;c<3;c++)
    for (int kh=0;kh<4;kh++)
      for (int kw=0;kw<4;kw++)
        a += x[((long)(nb*3+c)*64 + (iy*4+kh))*64 + (ix*4+kw)] * rw[((o*3+c)*4+kh)*4+kw];
  xr[idx] = a;
}

// static concat part for enc: channels 128..393 of ST_enc (stride 416)
__global__ void st_enc_k(const float* __restrict__ xr, const float* __restrict__ v,
                         const float* __restrict__ r, bf16* __restrict__ ST)
{
  long g = (long)blockIdx.x*256 + threadIdx.x;
  if (g >= (long)MTOT*266) return;
  int m = (int)(g / 266), ch = (int)(g % 266);
  int nb = m>>8, sp = m&255;
  float val;
  if (ch < 3)       val = xr[m*3 + ch];
  else if (ch < 10) val = v[nb*7 + ch - 3];
  else              val = r[((long)nb*256 + (ch-10))*256 + sp];
  ST[(long)m*416 + 128 + ch] = __float2bfloat16(val);
}

// static concat part for dec: channels 64..326 of ST_dec (stride 352)
__global__ void st_dec_k(const float* __restrict__ v, const float* __restrict__ r,
                         bf16* __restrict__ ST)
{
  long g = (long)blockIdx.x*256 + threadIdx.x;
  if (g >= (long)MTOT*263) return;
  int m = (int)(g / 263), ch = (int)(g % 263);
  int nb = m>>8, sp = m&255;
  float val;
  if (ch < 7) val = v[nb*7 + ch];
  else        val = r[((long)nb*256 + (ch-7))*256 + sp];
  ST[(long)m*352 + 64 + ch] = __float2bfloat16(val);
}

// LSTM pointwise: gates (f,i,o,s order, stride 512, bias included) -> c, h
__global__ void lstm_k(const bf16* __restrict__ gates, float* __restrict__ cbuf,
                       bf16* __restrict__ hpad)
{
  int idx = blockIdx.x*256 + threadIdx.x;   // exactly MTOT*128
  int m = idx >> 7, c = idx & 127;
  long gb = (long)m << 9;
  float f = __bfloat162float(gates[gb + c]);
  float i = __bfloat162float(gates[gb + 128 + c]);
  float o = __bfloat162float(gates[gb + 256 + c]);
  float s = __bfloat162float(gates[gb + 384 + c]);
  float cell = sigm_(f)*cbuf[idx] + sigm_(i)*tanhf(s);
  cbuf[idx] = cell;
  hpad[(pidx_(m)<<7) + c] = __float2bfloat16(sigm_(o)*tanhf(cell));
}

// z = q_mu + exp(0.5 q_lv)*eps (q = 4 post partials + bias); ADD z into
// fp8 sDec ch 0..63 ; KL partial per block.
__global__ void zkl4_k(const bf16* __restrict__ PP, const float* __restrict__ pb,
                       const float* __restrict__ prior, const float* __restrict__ eps_t,
                       unsigned char* __restrict__ sDec8, float* __restrict__ part)
{
  __shared__ float wsum[4];
  const long PL = (long)MTOT*128;
  int idx = blockIdx.x*256 + threadIdx.x;   // exactly MTOT*64
  int m = idx >> 6, c = idx & 63;
  float qm = pb[c], ql = pb[64 + c];
  #pragma unroll
  for (int z=0; z<4; ++z) {
    qm += __bfloat162float(PP[z*PL + ((long)m<<7) + c]);
    ql += __bfloat162float(PP[z*PL + ((long)m<<7) + 64 + c]);
  }
  long pbx = (long)m << 7;
  float pm = prior[pbx + c], pl = prior[pbx + 64 + c];
  int nb = m>>8, sp = m&255;
  float e = eps_t[((long)nb*64 + c)*256 + sp];
  float z = qm + expf(0.5f*ql)*e;
  long so = pidx_(m)*352 + c;
  sDec8[so] = f2fp8(fp82f(sDec8[so]) + z);
  float kl = expf(ql - pl) + (pm-qm)*(pm-qm)*expf(-pl) - 1.f + (pl - ql);
  #pragma unroll
  for (int off=32; off>0; off>>=1) kl += __shfl_down(kl, off);
  if ((threadIdx.x & 63) == 0) wsum[threadIdx.x >> 6] = kl;
  __syncthreads();
  if (threadIdx.x == 0)
    part[blockIdx.x] = wsum[0] + wsum[1] + wsum[2] + wsum[3];
}

// standalone canvas accumulate (final hDec state h^8)
__global__ __launch_bounds__(256)
void wrc_k(const bf16* __restrict__ hpad, const float* __restrict__ Wc,
           float* __restrict__ uc)
{
  __shared__ float Wl[128*48];
  for (int i = threadIdx.x; i < 128*48; i += 256) Wl[i] = Wc[i];
  __syncthreads();
  int t = threadIdx.x;
  int mloc = t >> 4, pix = t & 15;
  int m = (blockIdx.x<<4) + mloc;
  int nb = m>>8, iy=(m>>4)&15, ix=m&15;
  const bf16* h = hpad + (pidx_(m)<<7);
  float a0=0.f, a1=0.f, a2=0.f;
  for (int c=0;c<128;c++) {
    float hv = __bfloat162float(h[c]);
    const float* wl = Wl + c*48 + pix*3;
    a0 += hv*wl[0]; a1 += hv*wl[1]; a2 += hv*wl[2];
  }
  int ki = pix>>2, kj = pix&3;
  long ob = ((long)((nb<<6) + (iy<<2) + ki)*64 + (ix<<2) + kj)*3;
  uc[ob+0] += a0; uc[ob+1] += a1; uc[ob+2] += a2;
}

__global__ void canvas_k(const float* __restrict__ uc, const float* __restrict__ ob,
                         float* __restrict__ out)
{
  int idx = blockIdx.x*256 + threadIdx.x;   // exactly 786432, NCHW order
  int x = idx & 63, y = (idx>>6)&63;
  int rem = idx >> 12;
  int o = rem % 3, n = rem / 3;
  float v = uc[((long)((n<<6)+y)*64 + x)*3 + o] + ob[o];
  out[idx] = 1.f/(1.f+expf(-v));
}

// final KL: sum 8*4096 per-block partials, scale, write out[786432]
__global__ void klred_k(const float* __restrict__ part, float* __restrict__ out)
{
  __shared__ float wsum[4];
  float a = 0.f;
  for (int i = threadIdx.x; i < 32768; i += 256) a += part[i];
  #pragma unroll
  for (int off=32; off>0; off>>=1) a += __shfl_down(a, off);
  if ((threadIdx.x & 63) == 0) wsum[threadIdx.x >> 6] = a;
  __syncthreads();
  if (threadIdx.x == 0)
    out[786432] = (wsum[0] + wsum[1] + wsum[2] + wsum[3]) * (0.5f/64.f);
}

// ---------------------------------------------------------------------------
// workspace layout (bytes). Slots sized for the old bf16 footprints; fp8
// tenants (Bt8*, sEnc8, sDec8) use <= half of them. Gates at O_PG, PostP at
// O_PG+16.7MB (disjoint lifetimes within an iteration).
static const long O_BT_POST  = 0;                     // 128*3200*2
static const long O_BT_ENCT  = O_BT_POST  + 819200;   // 512*3200*2
static const long O_BT_DP    = O_BT_ENCT  + 3276800;  // 512*3200*2
static const long O_BT_ENCG  = O_BT_DP    + 3276800;  // fp8 512*10496
static const long O_BT_DECG  = O_BT_ENCG  + 10649600; // fp8 512*8832
static const long O_WCOMB    = O_BT_DECG  + 9011200;  // 6144*4
static const long O_XR       = O_WCOMB    + 24576;    // 49152*4
static const long O_KLP      = O_XR       + 196608;   // 32768*4
static const long O_STENC    = O_KLP      + 131072;   // 16384*416*2
static const long O_STDEC    = O_STENC    + 13631488; // 16384*352*2
static const long O_HENC     = O_STDEC    + 11534336; // 25600*128*2
static const long O_HDEC     = O_HENC     + 6553600;
static const long O_SENC     = O_HDEC     + 6553600;  // fp8 25600*416 (+overread pad)
static const long O_SDEC     = O_SENC     + 21299200; // fp8 25600*352 (+overread pad)
static const long O_CENC     = O_SDEC     + 18022400; // 16384*128*4
static const long O_CDEC     = O_CENC     + 8388608;
static const long O_PRIOR    = O_CDEC     + 8388608;  // 16384*128*4
static const long O_PG       = O_PRIOR    + 8388608;  // Gates 16.7MB + PostP 16.7MB
static const long O_UC       = O_PG       + 33554432; // 786432*4
static const long WS_TOTAL   = O_UC       + 3145728;  // ~167 MB

extern "C" void kernel_launch(void* const* d_in, const int* in_sizes, int n_in,
                              void* d_out, int out_size, void* d_ws, size_t ws_size,
                              hipStream_t stream)
{
  const float* x       = (const float*)d_in[0];
  const float* v       = (const float*)d_in[1];
  const float* r       = (const float*)d_in[2];
  const float* eps     = (const float*)d_in[3];
  const float* read_w  = (const float*)d_in[4];
  const float* write_w = (const float*)d_in[5];
  const float* prior_w = (const float*)d_in[6];
  const float* prior_b = (const float*)d_in[7];
  const float* post_w  = (const float*)d_in[8];
  const float* post_b  = (const float*)d_in[9];
  const float* enc_gw  = (const float*)d_in[10];
  const float* enc_gb  = (const float*)d_in[11];
  const float* enc_tw  = (const float*)d_in[12];
  const float* enc_tb  = (const float*)d_in[13];
  const float* dec_gw  = (const float*)d_in[14];
  const float* dec_gb  = (const float*)d_in[15];
  const float* dec_tw  = (const float*)d_in[16];
  const float* dec_tb  = (const float*)d_in[17];
  const float* obs_w   = (const float*)d_in[18];
  const float* obs_b   = (const float*)d_in[19];

  char* ws = (char*)d_ws;
  bf16* BtPost  = (bf16*)(ws + O_BT_POST);
  bf16* BtEncT  = (bf16*)(ws + O_BT_ENCT);
  bf16* BtDP    = (bf16*)(ws + O_BT_DP);
  unsigned char* Bt8EncG = (unsigned char*)(ws + O_BT_ENCG);
  unsigned char* Bt8DecG = (unsigned char*)(ws + O_BT_DECG);
  float* Wcomb  = (float*)(ws + O_WCOMB);
  float* XR     = (float*)(ws + O_XR);
  float* KLpart = (float*)(ws + O_KLP);
  bf16* STenc   = (bf16*)(ws + O_STENC);
  bf16* STdec   = (bf16*)(ws + O_STDEC);
  bf16* hEnc    = (bf16*)(ws + O_HENC);
  bf16* hDec    = (bf16*)(ws + O_HDEC);
  unsigned char* sEnc8 = (unsigned char*)(ws + O_SENC);
  unsigned char* sDec8 = (unsigned char*)(ws + O_SDEC);
  float* cEnc   = (float*)(ws + O_CENC);
  float* cDec   = (float*)(ws + O_CDEC);
  float* PriorO = (float*)(ws + O_PRIOR);
  bf16* Gates   = (bf16*)(ws + O_PG);
  bf16* PostP   = (bf16*)(ws + O_PG + 16777216);
  float* Ucomb  = (float*)(ws + O_UC);
  float* out    = (float*)d_out;

  size_t clr = (size_t)WS_TOTAL; if (clr > ws_size) clr = ws_size;
  hipMemsetAsync(d_ws, 0, clr, stream);

  // weight repacks
  repack_w_k<<<1600, 256, 0, stream>>>(post_w,  BtPost, 128, 128, 128, 128L*3200);
  repack_w_k<<<6400, 256, 0, stream>>>(enc_tw,  BtEncT, 394, 128, 128, 512L*3200);
  repack_w_k<<<4800, 256, 0, stream>>>(dec_tw,  BtDP,   327, 128, 128, 384L*3200);
  repack_w_k<<<1600, 256, 0, stream>>>(prior_w, BtDP + 384L*3200, 128, 128, 128, 128L*3200);
  repack_w8_k<<<20992, 256, 0, stream>>>(enc_gw, Bt8EncG, 512, 394, 416, 82*128, 512L*10496);
  repack_w8_k<<<17664, 256, 0, stream>>>(dec_gw, Bt8DecG, 512, 327, 352, 69*128, 512L*8832);
  wcomb_k<<<24, 256, 0, stream>>>(write_w, obs_w, Wcomb);
  xr_k<<<192, 256, 0, stream>>>(x, read_w, XR);
  st_enc_k<<<(int)(((long)MTOT*266 + 255)/256), 256, 0, stream>>>(XR, v, r, STenc);
  st_dec_k<<<(int)(((long)MTOT*263 + 255)/256), 256, 0, stream>>>(v, r, STdec);

  for (int t = 0; t < 8; ++t) {
    // merged: z=0 sDec8=decT(hDec)+tb+ST & PriorO ; z=1 sEnc8=encT(hEnc)+tb+ST+hDec
    // + fused wrc epilogue on current hDec (h^t; h^0 zero -> 0)
    conv_tp<<<dim3(64,4,2), 512, 0, stream>>>(
        hDec, BtDP, dec_tb, prior_b, PriorO, sDec8, STdec,
        hEnc, BtEncT, enc_tb, sEnc8, STenc, Wcomb, Ucomb);
    // enc gates: MX-fp8, K=128/step, 2 blocks/CU, bias fused
    conv_g8<416,82><<<dim3(128,4), 256, 0, stream>>>(sEnc8, Bt8EncG, enc_gb, Gates);
    lstm_k<<<8192, 256, 0, stream>>>(Gates, cEnc, hEnc);
    // post split-K=4 -> partial planes (bf16)
    conv_post<<<dim3(64,1,4), 512, 0, stream>>>(hEnc, BtPost, PostP);
    // z (sum partials + bias) -> add into fp8 sDec ch0..63 ; KL partials
    zkl4_k<<<4096, 256, 0, stream>>>(PostP, post_b, PriorO,
                                     eps + (long)t*64*64*256, sDec8,
                                     KLpart + (long)t*4096);
    // dec gates: MX-fp8
    conv_g8<352,69><<<dim3(128,4), 256, 0, stream>>>(sDec8, Bt8DecG, dec_gb, Gates);
    lstm_k<<<8192, 256, 0, stream>>>(Gates, cDec, hDec);
  }

  // final canvas contribution from h^8 (loop epilogues covered h^1..h^7)
  wrc_k<<<1024, 256, 0, stream>>>(hDec, Wcomb, Ucomb);
  canvas_k<<<3072, 256, 0, stream>>>(Ucomb, obs_b, out);
  klred_k<<<1, 256, 0, stream>>>(KLpart, out);
}

// Round 12
// 2685.480 us; speedup vs baseline: 1.5590x; 1.0659x over previous
//
#include <hip/hip_runtime.h>
#include <hip/hip_bf16.h>

using bf16 = __hip_bfloat16;
typedef __attribute__((ext_vector_type(8))) short short8;
typedef __attribute__((ext_vector_type(4))) float f32x4;
typedef __attribute__((ext_vector_type(8))) int i32x8;
typedef __attribute__((ext_vector_type(4))) int i32x4;

#define DEVI __device__ __forceinline__

#define MTOT 16384      // 64 * 16 * 16 output positions
#define PADS 25600      // 64 * 20 * 20 padded positions

DEVI float sigm_(float x){ return 1.f/(1.f+expf(-x)); }

DEVI long pidx_(int m){
  int nb = m>>8, iy=(m>>4)&15, ix=m&15;
  return (long)(nb*20 + iy + 2)*20 + (ix + 2);
}

DEVI unsigned char f2fp8(float x){
  int p = __builtin_amdgcn_cvt_pk_fp8_f32(x, 0.f, 0, false);
  return (unsigned char)(p & 0xFF);
}
DEVI float fp82f(unsigned char v){
  return __builtin_amdgcn_cvt_f32_fp8((int)v, 0);
}

// async global->LDS, 16B per lane. LDS dest = wave-uniform base + lane*16.
DEVI void async16(const void* g, void* l) {
  __builtin_amdgcn_global_load_lds(
      (__attribute__((address_space(1))) void*)(unsigned long long)g,
      (__attribute__((address_space(3))) void*)(unsigned int)(unsigned long long)l,
      16, 0, 0);
}

template<int N> DEVI void waitbar(){
  if constexpr (N==0)      asm volatile("s_waitcnt vmcnt(0)\ns_barrier" ::: "memory");
  else if constexpr (N==3) asm volatile("s_waitcnt vmcnt(3)\ns_barrier" ::: "memory");
  else                     asm volatile("s_waitcnt vmcnt(6)\ns_barrier" ::: "memory");
}

// ---------------------------------------------------------------------------
// MX-fp8 GEMM core (r11-proven). BM=128, BN=128, BK=128, 4 waves 2Mx2N,
// double-buffered 64KB LDS -> 2 blocks/CU. A8: padded NHWC fp8 [PADS][CA].
// Bt8: [512][NS*128] fp8, weights pre-scaled x32; MFMA scale_b=122 (2^-5)
// undoes exactly; scale_a=127. Rows 128B, chunk^=(row&7) swizzle via
// pre-swizzled source. Stage-after-barrier + vmcnt(0): load in flight one
// full phase before its wait.
// Produces acc[4][4]; epilogue left to caller.
// ---------------------------------------------------------------------------
template<int CA, int NS>
DEVI void g8_core(const unsigned char* __restrict__ A8,
                  const unsigned char* __restrict__ Bt8,
                  int m0, int n0, unsigned char* AsB, unsigned char* BsB,
                  f32x4 (&acc)[4][4])
{
  constexpr int Kp8 = NS*128;
  const int tid = threadIdx.x;
  const int wv = tid>>6, ln = tid&63;

  const int rr = tid>>3;
  const int lc = (tid&7) ^ (rr&7);
  long paRC[4], pbR[4];
  #pragma unroll
  for (int i=0;i<4;i++){
    int m = m0 + rr + (i<<5);
    paRC[i] = (long)(((m>>8)*20 + ((m>>4)&15))*20 + (m&15)) * CA;
    pbR[i]  = (long)(n0 + rr + (i<<5))*Kp8 + lc*16;
  }

  int cc = lc*16, tp = 0, ks = 0;
  auto stage = [&](int d){
    const int shiftC = ((tp/5)*20 + (tp%5)) * CA;
    char* la = (char*)AsB + d*16384 + (wv<<10);
    char* lb = (char*)BsB + d*16384 + (wv<<10);
    #pragma unroll
    for (int i=0;i<4;i++) async16(A8 + paRC[i] + shiftC + cc, la + i*4096);
    #pragma unroll
    for (int i=0;i<4;i++) async16(Bt8 + pbR[i] + ks, lb + i*4096);
    cc += 128; if (cc >= CA){ cc -= CA; tp++; }
    ks += 128;
  };

  const int wm = wv>>1, wn = wv&1;
  const int rA0 = (wm<<6) + (ln&15);
  const int rB0 = (wn<<6) + (ln&15);
  const int xa = ln&7;
  const int q2 = (ln>>4)<<1;
  const int c0 = ((q2    ) ^ xa)<<4;
  const int c1 = ((q2 | 1) ^ xa)<<4;

  stage(0);
  for (int t=0; t<NS; ++t) {
    asm volatile("s_waitcnt vmcnt(0)\ns_barrier" ::: "memory");
    if (t+1 < NS) stage((t+1)&1);

    const char* as_ = (const char*)AsB + (t&1)*16384;
    const char* bs_ = (const char*)BsB + (t&1)*16384;
    i32x8 af[4], bfr[4];
    #pragma unroll
    for (int f=0; f<4; f++){
      const char* p = as_ + ((rA0 + (f<<4))<<7);
      ((i32x4*)&af[f])[0] = *(const i32x4*)(p + c0);
      ((i32x4*)&af[f])[1] = *(const i32x4*)(p + c1);
    }
    #pragma unroll
    for (int f=0; f<4; f++){
      const char* p = bs_ + ((rB0 + (f<<4))<<7);
      ((i32x4*)&bfr[f])[0] = *(const i32x4*)(p + c0);
      ((i32x4*)&bfr[f])[1] = *(const i32x4*)(p + c1);
    }
    __builtin_amdgcn_s_setprio(1);
    #pragma unroll
    for (int mf=0; mf<4; mf++)
      #pragma unroll
      for (int nf=0; nf<4; nf++)
        acc[mf][nf] = __builtin_amdgcn_mfma_scale_f32_16x16x128_f8f6f4(
            af[mf], bfr[nf], acc[mf][nf], 0, 0, 0, 127, 0, 122);
    __builtin_amdgcn_s_setprio(0);
  }
}

// gates GEMM (r11 champion): bf16 out stride 512 + bias.
template<int CA, int NS>
__global__ __launch_bounds__(256)
void conv_g8(const unsigned char* __restrict__ A8,
             const unsigned char* __restrict__ Bt8,
             const float* __restrict__ bias, bf16* __restrict__ outB)
{
  __shared__ alignas(16) unsigned char As[2][16384];
  __shared__ alignas(16) unsigned char Bs[2][16384];
  const int m0 = blockIdx.x<<7, n0 = blockIdx.y<<7;
  f32x4 acc[4][4] = {};
  g8_core<CA,NS>(A8, Bt8, m0, n0, &As[0][0], &Bs[0][0], acc);

  const int tid = threadIdx.x;
  const int wv = tid>>6, ln = tid&63;
  const int mb = m0 + ((wv>>1)<<6);
  const int nb = n0 + ((wv&1)<<6);
  const int ml = (ln>>4)<<2;
  const int nl = ln&15;
  #pragma unroll
  for (int mf=0; mf<4; mf++)
    #pragma unroll
    for (int j=0; j<4; j++) {
      const int m = mb + (mf<<4) + ml + j;
      #pragma unroll
      for (int nf=0; nf<4; nf++) {
        const int n = nb + (nf<<4) + nl;
        outB[((long)m<<9) + n] = __float2bfloat16(acc[mf][nf][j] + bias[n]);
      }
    }
}

// merged fp8 T-convs: z=0 decT+prior (A=h8Dec, B=Bt8DP):
//   n<352 -> sDec8 fp8 (+tb(n<327)+ST) ; n>=384 -> PriorO f32 (+prior_b)
// z=1 encT (A=h8Enc, B=Bt8EncT):
//   n<416 -> sEnc8 fp8 (+tb(n<394)+ST+hDec(n<128))
// + wrc canvas epilogue on current bf16 hDec (h^t; h^0 zero -> 0).
__global__ __launch_bounds__(256)
void conv_tp8(const unsigned char* __restrict__ h8Dec,
              const unsigned char* __restrict__ h8Enc,
              const unsigned char* __restrict__ Bt8DP,
              const unsigned char* __restrict__ Bt8EncT,
              const float* __restrict__ dec_tb, const float* __restrict__ prior_b,
              const float* __restrict__ enc_tb,
              float* __restrict__ PriorO,
              unsigned char* __restrict__ sDec8, const bf16* __restrict__ STdec,
              unsigned char* __restrict__ sEnc8, const bf16* __restrict__ STenc,
              const bf16* __restrict__ hDecB,
              const float* __restrict__ Wc, float* __restrict__ uc)
{
  __shared__ alignas(16) unsigned char As[2][16384];
  __shared__ alignas(16) unsigned char Bs[2][16384];
  const int z = blockIdx.z;
  const int m0 = blockIdx.x<<7, n0 = blockIdx.y<<7;
  f32x4 acc[4][4] = {};
  if (z == 0) g8_core<128,25>(h8Dec, Bt8DP,   m0, n0, &As[0][0], &Bs[0][0], acc);
  else        g8_core<128,25>(h8Enc, Bt8EncT, m0, n0, &As[0][0], &Bs[0][0], acc);

  const int tid = threadIdx.x;
  const int wv = tid>>6, ln = tid&63;
  const int mb = m0 + ((wv>>1)<<6);
  const int nb = n0 + ((wv&1)<<6);
  const int ml = (ln>>4)<<2;
  const int nl = ln&15;
  #pragma unroll
  for (int mf=0; mf<4; mf++)
    #pragma unroll
    for (int j=0; j<4; j++) {
      const int m = mb + (mf<<4) + ml + j;
      const long pI = pidx_(m);
      #pragma unroll
      for (int nf=0; nf<4; nf++) {
        const int n = nb + (nf<<4) + nl;
        const float v = acc[mf][nf][j];
        if (z == 0) {
          if (n < 352) {
            float b  = (n < 327) ? dec_tb[n] : 0.f;
            float st = __bfloat162float(STdec[(long)m*352 + n]);
            sDec8[pI*352 + n] = f2fp8(v + b + st);
          } else if (n >= 384) {
            PriorO[((long)m<<7) + (n-384)] = v + prior_b[n-384];
          }
        } else {
          if (n < 416) {
            float b  = (n < 394) ? enc_tb[n] : 0.f;
            float st = __bfloat162float(STenc[(long)m*416 + n]);
            float e  = (n < 128) ? __bfloat162float(hDecB[(pI<<7) + n]) : 0.f;
            sEnc8[pI*416 + n] = f2fp8(v + b + st + e);
          }
        }
      }
    }

  // wrc epilogue: 1024 blocks x 16 m-rows covers MTOT exactly.
  const int gid = blockIdx.z*512 + blockIdx.y*128 + blockIdx.x;
  const int m = (gid<<4) + (tid>>4);
  const int pix = tid&15;
  const int nb2 = m>>8, iy=(m>>4)&15, ix=m&15;
  const bf16* __restrict__ h = hDecB + (pidx_(m)<<7);
  float a0=0.f, a1=0.f, a2=0.f;
  #pragma unroll 4
  for (int c=0;c<128;c++) {
    float hv = __bfloat162float(h[c]);
    const float* wl = Wc + c*48 + pix*3;
    a0 += hv*wl[0]; a1 += hv*wl[1]; a2 += hv*wl[2];
  }
  const int ki = pix>>2, kj = pix&3;
  long ob = ((long)((nb2<<6) + (iy<<2) + ki)*64 + (ix<<2) + kj)*3;
  uc[ob+0] += a0; uc[ob+1] += a1; uc[ob+2] += a2;
}

// ---------------------------------------------------------------------------
// r7-proven 8-wave bf16 conv body — used only by conv_post now.
// EPI 6 = bf16 PARTIAL out stride 128, no bias.
// ---------------------------------------------------------------------------
template<int CA, int EPI>
DEVI void conv_body(const bf16* __restrict__ A, const bf16* __restrict__ Bt,
                    bf16* __restrict__ outB,
                    int s0, int s1, int m0, int n0,
                    bf16* AsBase, bf16* BsBase)
{
  constexpr int Kp = 25*CA;
  const int NS = s1 - s0;

  const int tid = threadIdx.x;
  const int wv = tid>>6, ln = tid&63;

  const int rA = tid>>2;
  const int qs = ((tid&3) ^ ((rA>>1)&3))<<3;
  const int mA0 = m0 + rA, mA1 = m0 + 128 + rA;
  const long paA0 = ((long)(((mA0>>8)*20 + ((mA0>>4)&15))*20 + (mA0&15)))*CA + qs;
  const long paA1 = ((long)(((mA1>>8)*20 + ((mA1>>4)&15))*20 + (mA1&15)))*CA + qs;
  const long pbB  = (long)(n0 + rA)*Kp + qs;

  int kk0 = s0*32;
  int c0 = kk0 % CA;
  int tap = kk0 / CA;
  int kh = tap/5, kw = tap%5;
  int ks = kk0;

  auto stage = [&](int d){
    const long sh = (long)(kh*20 + kw)*CA + c0;
    char* la = (char*)AsBase + d*16384 + (wv<<10);
    char* lb = (char*)BsBase + d*8192  + (wv<<10);
    async16(A + paA0 + sh, la);
    async16(A + paA1 + sh, la + 8192);
    async16(Bt + pbB + ks, lb);
    ks += 32;
    c0 += 32; if (c0==CA){ c0=0; if(++kw==5){kw=0; ++kh;} }
  };

  f32x4 acc[4][4] = {};
  const int wm = wv>>1, wn = wv&1;
  const int rowA = (wm<<6) + (ln&15);
  const int rowB = (wn<<6) + (ln&15);
  const int kqA = (((ln>>4) ^ ((rowA>>1)&3))<<4);
  const int kqB = (((ln>>4) ^ ((rowB>>1)&3))<<4);

  stage(0); stage(1);
  int bc = 0, bs = 2;
  for (int t=0; t<NS; ++t) {
    if (t+1 < NS) waitbar<3>();
    else          waitbar<0>();
    if (t+2 < NS) stage(bs);

    const char* as_ = (const char*)AsBase + bc*16384;
    const char* bs_ = (const char*)BsBase + bc*8192;
    short8 af[4], bfr[4];
    #pragma unroll
    for (int mf=0; mf<4; mf++)
      af[mf] = *(const short8*)(as_ + ((rowA + (mf<<4))<<6) + kqA);
    #pragma unroll
    for (int nf=0; nf<4; nf++)
      bfr[nf] = *(const short8*)(bs_ + ((rowB + (nf<<4))<<6) + kqB);
    __builtin_amdgcn_s_setprio(1);
    #pragma unroll
    for (int mf=0; mf<4; mf++)
      #pragma unroll
      for (int nf=0; nf<4; nf++)
        acc[mf][nf] = __builtin_amdgcn_mfma_f32_16x16x32_bf16(af[mf], bfr[nf], acc[mf][nf], 0,0,0);
    __builtin_amdgcn_s_setprio(0);
    bc = (bc==2)?0:bc+1; bs = (bs==2)?0:bs+1;
  }

  const int mb = m0 + (wm<<6);
  const int nb = n0 + (wn<<6);
  const int ml = (ln>>4)<<2;
  const int nl = ln&15;
  #pragma unroll
  for (int mf=0; mf<4; mf++)
    #pragma unroll
    for (int j=0; j<4; j++) {
      const int m = mb + (mf<<4) + ml + j;
      #pragma unroll
      for (int nf=0; nf<4; nf++) {
        const int n = nb + (nf<<4) + nl;
        outB[((long)m<<7) + n] = __float2bfloat16(acc[mf][nf][j]);
      }
    }
}

// post GEMM split-K=4: grid (64,1,4); partial planes of 16384x128 bf16.
__global__ __launch_bounds__(512)
void conv_post(const bf16* __restrict__ hEnc, const bf16* __restrict__ BtPost,
               bf16* __restrict__ PP)
{
  __shared__ alignas(16) bf16 As[3][256*32];
  __shared__ alignas(16) bf16 Bs[3][128*32];
  const int z = blockIdx.z;
  conv_body<128,6>(hEnc, BtPost, PP + (long)z*MTOT*128,
                   z*25, z*25+25, blockIdx.x<<8, 0, &As[0][0], &Bs[0][0]);
}

// OIHW f32 -> Bt[n=o][k=(kh*5+kw)*CA + c] bf16, rows o>=O / cols c>=I zeroed.
__global__ void repack_w_k(const float* __restrict__ w, bf16* __restrict__ Bt,
                           int O, int I, int CA, long total)
{
  long e = (long)blockIdx.x*256 + threadIdx.x;
  if (e >= total) return;
  const int Kp = 25*CA;
  int o = (int)(e / Kp);
  int k = (int)(e % Kp);
  int blk = k / CA, c = k % CA;
  float v = 0.f;
  if (o < O && c < I) v = w[((long)o*I + c)*25 + blk];
  Bt[e] = __float2bfloat16(v);
}

// fp8 repack with x32 scale (undone by MFMA scale_b = 2^-5), K padded to Kp8.
__global__ void repack_w8_k(const float* __restrict__ w, unsigned char* __restrict__ Bt,
                            int O, int I, int CA, int Kp8, long total)
{
  long e = (long)blockIdx.x*256 + threadIdx.x;
  if (e >= total) return;
  int o = (int)(e / Kp8);
  int k = (int)(e % Kp8);
  float v = 0.f;
  if (k < 25*CA) {
    int blk = k / CA, c = k % CA;
    if (o < O && c < I) v = w[((long)o*I + c)*25 + blk] * 32.0f;
  }
  Bt[e] = f2fp8(v);
}

// Wcomb[c][pix*3+o] = sum_m write_w[c,m,ki,kj] * obs_w[o,m]   (pix = ki*4+kj)
__global__ void wcomb_k(const float* __restrict__ ww, const float* __restrict__ ow,
                        float* __restrict__ Wc)
{
  int idx = blockIdx.x*256 + threadIdx.x;
  if (idx >= 128*48) return;
  int c = idx / 48, rst = idx % 48;
  int pix = rst / 3, o = rst % 3;
  int ki = pix >> 2, kj = pix & 3;
  float a = 0.f;
  for (int mm=0; mm<128; mm++)
    a += ww[(((long)c*128 + mm)*4 + ki)*4 + kj] * ow[o*128 + mm];
  Wc[idx] = a;
}

// xr = conv(x, read_w, stride 4), xr[m*3+o]
__global__ void xr_k(const float* __restrict__ x, const float* __restrict__ rw,
                     float* __restrict__ xr)
{
  int idx = blockIdx.x*256 + threadIdx.x;
  if (idx >= MTOT*3) return;
  int m = idx / 3, o = idx % 3;
  int nb = m>>8, iy=(m>>4)&15, ix=m&15;
  float a = 0.f;
  for (int c=0;c<3;c++)
    for (int kh=0;kh<4;kh++)
      for (int kw=0;kw<4;kw++)
        a += x[((long)(nb*3+c)*64 + (iy*4+kh))*64 + (ix*4+kw)] * rw[((o*3+c)*4+kh)*4+kw];
  xr[idx] = a;
}

// static concat part for enc: channels 128..393 of ST_enc (stride 416)
__global__ void st_enc_k(const float* __restrict__ xr, const float* __restrict__ v,
                         const float* __restrict__ r, bf16* __restrict__ ST)
{
  long g = (long)blockIdx.x*256 + threadIdx.x;
  if (g >= (long)MTOT*266) return;
  int m = (int)(g / 266), ch = (int)(g % 266);
  int nb = m>>8, sp = m&255;
  float val;
  if (ch < 3)       val = xr[m*3 + ch];
  else if (ch < 10) val = v[nb*7 + ch - 3];
  else              val = r[((long)nb*256 + (ch-10))*256 + sp];
  ST[(long)m*416 + 128 + ch] = __float2bfloat16(val);
}

// static concat part for dec: channels 64..326 of ST_dec (stride 352)
__global__ void st_dec_k(const float* __restrict__ v, const float* __restrict__ r,
                         bf16* __restrict__ ST)
{
  long g = (long)blockIdx.x*256 + threadIdx.x;
  if (g >= (long)MTOT*263) return;
  int m = (int)(g / 263), ch = (int)(g % 263);
  int nb = m>>8, sp = m&255;
  float val;
  if (ch < 7) val = v[nb*7 + ch];
  else        val = r[((long)nb*256 + (ch-7))*256 + sp];
  ST[(long)m*352 + 64 + ch] = __float2bfloat16(val);
}

// LSTM pointwise: gates (f,i,o,s, stride 512, bias included) -> c, h (bf16+fp8)
__global__ void lstm_k(const bf16* __restrict__ gates, float* __restrict__ cbuf,
                       bf16* __restrict__ hpad, unsigned char* __restrict__ h8)
{
  int idx = blockIdx.x*256 + threadIdx.x;   // exactly MTOT*128
  int m = idx >> 7, c = idx & 127;
  long gb = (long)m << 9;
  float f = __bfloat162float(gates[gb + c]);
  float i = __bfloat162float(gates[gb + 128 + c]);
  float o = __bfloat162float(gates[gb + 256 + c]);
  float s = __bfloat162float(gates[gb + 384 + c]);
  float cell = sigm_(f)*cbuf[idx] + sigm_(i)*tanhf(s);
  cbuf[idx] = cell;
  float h = sigm_(o)*tanhf(cell);
  long hp = (pidx_(m)<<7) + c;
  hpad[hp] = __float2bfloat16(h);
  h8[hp] = f2fp8(h);
}

// z = q_mu + exp(0.5 q_lv)*eps (q = 4 post partials + bias); ADD z into
// fp8 sDec ch 0..63 ; KL partial per block.
__global__ void zkl4_k(const bf16* __restrict__ PP, const float* __restrict__ pb,
                       const float* __restrict__ prior, const float* __restrict__ eps_t,
                       unsigned char* __restrict__ sDec8, float* __restrict__ part)
{
  __shared__ float wsum[4];
  const long PL = (long)MTOT*128;
  int idx = blockIdx.x*256 + threadIdx.x;   // exactly MTOT*64
  int m = idx >> 6, c = idx & 63;
  float qm = pb[c], ql = pb[64 + c];
  #pragma unroll
  for (int z=0; z<4; ++z) {
    qm += __bfloat162float(PP[z*PL + ((long)m<<7) + c]);
    ql += __bfloat162float(PP[z*PL + ((long)m<<7) + 64 + c]);
  }
  long pbx = (long)m << 7;
  float pm = prior[pbx + c], pl = prior[pbx + 64 + c];
  int nb = m>>8, sp = m&255;
  float e = eps_t[((long)nb*64 + c)*256 + sp];
  float z = qm + expf(0.5f*ql)*e;
  long so = pidx_(m)*352 + c;
  sDec8[so] = f2fp8(fp82f(sDec8[so]) + z);
  float kl = expf(ql - pl) + (pm-qm)*(pm-qm)*expf(-pl) - 1.f + (pl - ql);
  #pragma unroll
  for (int off=32; off>0; off>>=1) kl += __shfl_down(kl, off);
  if ((threadIdx.x & 63) == 0) wsum[threadIdx.x >> 6] = kl;
  __syncthreads();
  if (threadIdx.x == 0)
    part[blockIdx.x] = wsum[0] + wsum[1] + wsum[2] + wsum[3];
}

// standalone canvas accumulate (final hDec state h^8)
__global__ __launch_bounds__(256)
void wrc_k(const bf16* __restrict__ hpad, const float* __restrict__ Wc,
           float* __restrict__ uc)
{
  __shared__ float Wl[128*48];
  for (int i = threadIdx.x; i < 128*48; i += 256) Wl[i] = Wc[i];
  __syncthreads();
  int t = threadIdx.x;
  int mloc = t >> 4, pix = t & 15;
  int m = (blockIdx.x<<4) + mloc;
  int nb = m>>8, iy=(m>>4)&15, ix=m&15;
  const bf16* h = hpad + (pidx_(m)<<7);
  float a0=0.f, a1=0.f, a2=0.f;
  for (int c=0;c<128;c++) {
    float hv = __bfloat162float(h[c]);
    const float* wl = Wl + c*48 + pix*3;
    a0 += hv*wl[0]; a1 += hv*wl[1]; a2 += hv*wl[2];
  }
  int ki = pix>>2, kj = pix&3;
  long ob = ((long)((nb<<6) + (iy<<2) + ki)*64 + (ix<<2) + kj)*3;
  uc[ob+0] += a0; uc[ob+1] += a1; uc[ob+2] += a2;
}

__global__ void canvas_k(const float* __restrict__ uc, const float* __restrict__ ob,
                         float* __restrict__ out)
{
  int idx = blockIdx.x*256 + threadIdx.x;   // exactly 786432, NCHW order
  int x = idx & 63, y = (idx>>6)&63;
  int rem = idx >> 12;
  int o = rem % 3, n = rem / 3;
  float v = uc[((long)((n<<6)+y)*64 + x)*3 + o] + ob[o];
  out[idx] = 1.f/(1.f+expf(-v));
}

// final KL: sum 8*4096 per-block partials, scale, write out[786432]
__global__ void klred_k(const float* __restrict__ part, float* __restrict__ out)
{
  __shared__ float wsum[4];
  float a = 0.f;
  for (int i = threadIdx.x; i < 32768; i += 256) a += part[i];
  #pragma unroll
  for (int off=32; off>0; off>>=1) a += __shfl_down(a, off);
  if ((threadIdx.x & 63) == 0) wsum[threadIdx.x >> 6] = a;
  __syncthreads();
  if (threadIdx.x == 0)
    out[786432] = (wsum[0] + wsum[1] + wsum[2] + wsum[3]) * (0.5f/64.f);
}

// ---------------------------------------------------------------------------
// workspace layout (bytes). fp8 tenants reuse oversized bf16-era slots.
static const long O_BT_POST  = 0;                     // bf16 128*3200*2
static const long O_BT_ENCT  = O_BT_POST  + 819200;   // fp8 512*3200 (1.6MB in 3.2MB slot)
static const long O_BT_DP    = O_BT_ENCT  + 3276800;  // fp8 512*3200
static const long O_BT_ENCG  = O_BT_DP    + 3276800;  // fp8 512*10496
static const long O_BT_DECG  = O_BT_ENCG  + 10649600; // fp8 512*8832
static const long O_WCOMB    = O_BT_DECG  + 9011200;  // 6144*4
static const long O_XR       = O_WCOMB    + 24576;    // 49152*4
static const long O_KLP      = O_XR       + 196608;   // 32768*4
static const long O_STENC    = O_KLP      + 131072;   // 16384*416*2
static const long O_STDEC    = O_STENC    + 13631488; // 16384*352*2
static const long O_HENC     = O_STDEC    + 11534336; // bf16 25600*128*2
static const long O_HDEC     = O_HENC     + 6553600;
static const long O_SENC     = O_HDEC     + 6553600;  // fp8 25600*416
static const long O_SDEC     = O_SENC     + 21299200; // fp8 25600*352
static const long O_CENC     = O_SDEC     + 18022400; // 16384*128*4
static const long O_CDEC     = O_CENC     + 8388608;
static const long O_PRIOR    = O_CDEC     + 8388608;  // 16384*128*4
static const long O_H8E      = O_PRIOR    + 8388608;  // fp8 25600*128
static const long O_H8D      = O_H8E      + 3276800;
static const long O_PG       = O_H8D      + 3276800;  // Gates 16.7MB + PostP 16.7MB
static const long O_UC       = O_PG       + 33554432; // 786432*4
static const long WS_TOTAL   = O_UC       + 3145728;  // ~174 MB

extern "C" void kernel_launch(void* const* d_in, const int* in_sizes, int n_in,
                              void* d_out, int out_size, void* d_ws, size_t ws_size,
                              hipStream_t stream)
{
  const float* x       = (const float*)d_in[0];
  const float* v       = (const float*)d_in[1];
  const float* r       = (const float*)d_in[2];
  const float* eps     = (const float*)d_in[3];
  const float* read_w  = (const float*)d_in[4];
  const float* write_w = (const float*)d_in[5];
  const float* prior_w = (const float*)d_in[6];
  const float* prior_b = (const float*)d_in[7];
  const float* post_w  = (const float*)d_in[8];
  const float* post_b  = (const float*)d_in[9];
  const float* enc_gw  = (const float*)d_in[10];
  const float* enc_gb  = (const float*)d_in[11];
  const float* enc_tw  = (const float*)d_in[12];
  const float* enc_tb  = (const float*)d_in[13];
  const float* dec_gw  = (const float*)d_in[14];
  const float* dec_gb  = (const float*)d_in[15];
  const float* dec_tw  = (const float*)d_in[16];
  const float* dec_tb  = (const float*)d_in[17];
  const float* obs_w   = (const float*)d_in[18];
  const float* obs_b   = (const float*)d_in[19];

  char* ws = (char*)d_ws;
  bf16* BtPost  = (bf16*)(ws + O_BT_POST);
  unsigned char* Bt8EncT = (unsigned char*)(ws + O_BT_ENCT);
  unsigned char* Bt8DP   = (unsigned char*)(ws + O_BT_DP);
  unsigned char* Bt8EncG = (unsigned char*)(ws + O_BT_ENCG);
  unsigned char* Bt8DecG = (unsigned char*)(ws + O_BT_DECG);
  float* Wcomb  = (float*)(ws + O_WCOMB);
  float* XR     = (float*)(ws + O_XR);
  float* KLpart = (float*)(ws + O_KLP);
  bf16* STenc   = (bf16*)(ws + O_STENC);
  bf16* STdec   = (bf16*)(ws + O_STDEC);
  bf16* hEnc    = (bf16*)(ws + O_HENC);
  bf16* hDec    = (bf16*)(ws + O_HDEC);
  unsigned char* sEnc8 = (unsigned char*)(ws + O_SENC);
  unsigned char* sDec8 = (unsigned char*)(ws + O_SDEC);
  float* cEnc   = (float*)(ws + O_CENC);
  float* cDec   = (float*)(ws + O_CDEC);
  float* PriorO = (float*)(ws + O_PRIOR);
  unsigned char* h8Enc = (unsigned char*)(ws + O_H8E);
  unsigned char* h8Dec = (unsigned char*)(ws + O_H8D);
  bf16* Gates   = (bf16*)(ws + O_PG);
  bf16* PostP   = (bf16*)(ws + O_PG + 16777216);
  float* Ucomb  = (float*)(ws + O_UC);
  float* out    = (float*)d_out;

  size_t clr = (size_t)WS_TOTAL; if (clr > ws_size) clr = ws_size;
  hipMemsetAsync(d_ws, 0, clr, stream);

  // weight repacks
  repack_w_k<<<1600, 256, 0, stream>>>(post_w, BtPost, 128, 128, 128, 128L*3200);
  repack_w8_k<<<6400, 256, 0, stream>>>(enc_tw, Bt8EncT, 394, 128, 128, 3200, 512L*3200);
  repack_w8_k<<<4800, 256, 0, stream>>>(dec_tw, Bt8DP, 327, 128, 128, 3200, 384L*3200);
  repack_w8_k<<<1600, 256, 0, stream>>>(prior_w, Bt8DP + 384L*3200, 128, 128, 128, 3200, 128L*3200);
  repack_w8_k<<<20992, 256, 0, stream>>>(enc_gw, Bt8EncG, 512, 394, 416, 82*128, 512L*10496);
  repack_w8_k<<<17664, 256, 0, stream>>>(dec_gw, Bt8DecG, 512, 327, 352, 69*128, 512L*8832);
  wcomb_k<<<24, 256, 0, stream>>>(write_w, obs_w, Wcomb);
  xr_k<<<192, 256, 0, stream>>>(x, read_w, XR);
  st_enc_k<<<(int)(((long)MTOT*266 + 255)/256), 256, 0, stream>>>(XR, v, r, STenc);
  st_dec_k<<<(int)(((long)MTOT*263 + 255)/256), 256, 0, stream>>>(v, r, STdec);

  for (int t = 0; t < 8; ++t) {
    // merged fp8 T-convs (decT+prior | encT) + wrc epilogue on current hDec
    conv_tp8<<<dim3(128,4,2), 256, 0, stream>>>(
        h8Dec, h8Enc, Bt8DP, Bt8EncT, dec_tb, prior_b, enc_tb,
        PriorO, sDec8, STdec, sEnc8, STenc, hDec, Wcomb, Ucomb);
    // enc gates: MX-fp8
    conv_g8<416,82><<<dim3(128,4), 256, 0, stream>>>(sEnc8, Bt8EncG, enc_gb, Gates);
    lstm_k<<<8192, 256, 0, stream>>>(Gates, cEnc, hEnc, h8Enc);
    // post split-K=4 -> partial planes (bf16, accuracy-critical)
    conv_post<<<dim3(64,1,4), 512, 0, stream>>>(hEnc, BtPost, PostP);
    // z (sum partials + bias) -> add into fp8 sDec ch0..63 ; KL partials
    zkl4_k<<<4096, 256, 0, stream>>>(PostP, post_b, PriorO,
                                     eps + (long)t*64*64*256, sDec8,
                                     KLpart + (long)t*4096);
    // dec gates: MX-fp8
    conv_g8<352,69><<<dim3(128,4), 256, 0, stream>>>(sDec8, Bt8DecG, dec_gb, Gates);
    lstm_k<<<8192, 256, 0, stream>>>(Gates, cDec, hDec, h8Dec);
  }

  // final canvas contribution from h^8 (loop epilogues covered h^1..h^7)
  wrc_k<<<1024, 256, 0, stream>>>(hDec, Wcomb, Ucomb);
  canvas_k<<<3072, 256, 0, stream>>>(Ucomb, obs_b, out);
  klred_k<<<1, 256, 0, stream>>>(KLpart, out);
}

// Round 14
// 2619.593 us; speedup vs baseline: 1.5982x; 1.0252x over previous
//
#include <hip/hip_runtime.h>
#include <hip/hip_bf16.h>

using bf16 = __hip_bfloat16;
typedef __attribute__((ext_vector_type(8))) short short8;
typedef __attribute__((ext_vector_type(4))) float f32x4;
typedef __attribute__((ext_vector_type(8))) int i32x8;
typedef __attribute__((ext_vector_type(4))) int i32x4;
typedef __attribute__((ext_vector_type(2))) int i32x2;

#define DEVI __device__ __forceinline__

#define MTOT 16384      // 64 * 16 * 16 output positions
#define PADS 25600      // 64 * 20 * 20 padded positions

DEVI float sigm_(float x){ return 1.f/(1.f+expf(-x)); }

// bf16 (as raw short) -> f32: exact, just a 16-bit shift.
DEVI float s2f(short v){
  unsigned u = ((unsigned)(unsigned short)v) << 16;
  return __builtin_bit_cast(float, u);
}

DEVI long pidx_(int m){
  int nb = m>>8, iy=(m>>4)&15, ix=m&15;
  return (long)(nb*20 + iy + 2)*20 + (ix + 2);
}

DEVI unsigned char f2fp8(float x){
  int p = __builtin_amdgcn_cvt_pk_fp8_f32(x, 0.f, 0, false);
  return (unsigned char)(p & 0xFF);
}
DEVI float fp82f(unsigned char v){
  return __builtin_amdgcn_cvt_f32_fp8((int)v, 0);
}

// async global->LDS, 16B per lane. LDS dest = wave-uniform base + lane*16.
DEVI void async16(const void* g, void* l) {
  __builtin_amdgcn_global_load_lds(
      (__attribute__((address_space(1))) void*)(unsigned long long)g,
      (__attribute__((address_space(3))) void*)(unsigned int)(unsigned long long)l,
      16, 0, 0);
}

template<int N> DEVI void waitbar(){
  if constexpr (N==0)      asm volatile("s_waitcnt vmcnt(0)\ns_barrier" ::: "memory");
  else if constexpr (N==3) asm volatile("s_waitcnt vmcnt(3)\ns_barrier" ::: "memory");
  else                     asm volatile("s_waitcnt vmcnt(6)\ns_barrier" ::: "memory");
}

// ---------------------------------------------------------------------------
// MX-fp8 GEMM core (r11-proven). BM=128, BN=128, BK=128, 4 waves 2Mx2N,
// double-buffered 64KB LDS -> 2 blocks/CU. A8: padded NHWC fp8 [PADS][CA].
// Bt8: [512][NS*128] fp8, weights pre-scaled x32; MFMA scale_b=122 (2^-5)
// undoes exactly; scale_a=127. Rows 128B, chunk^=(row&7) swizzle via
// pre-swizzled source. Stage-after-barrier + vmcnt(0): load in flight one
// full phase before its wait.
// ---------------------------------------------------------------------------
template<int CA, int NS>
DEVI void g8_core(const unsigned char* __restrict__ A8,
                  const unsigned char* __restrict__ Bt8,
                  int m0, int n0, unsigned char* AsB, unsigned char* BsB,
                  f32x4 (&acc)[4][4])
{
  constexpr int Kp8 = NS*128;
  const int tid = threadIdx.x;
  const int wv = tid>>6, ln = tid&63;

  const int rr = tid>>3;
  const int lc = (tid&7) ^ (rr&7);
  long paRC[4], pbR[4];
  #pragma unroll
  for (int i=0;i<4;i++){
    int m = m0 + rr + (i<<5);
    paRC[i] = (long)(((m>>8)*20 + ((m>>4)&15))*20 + (m&15)) * CA;
    pbR[i]  = (long)(n0 + rr + (i<<5))*Kp8 + lc*16;
  }

  int cc = lc*16, tp = 0, ks = 0;
  auto stage = [&](int d){
    const int shiftC = ((tp/5)*20 + (tp%5)) * CA;
    char* la = (char*)AsB + d*16384 + (wv<<10);
    char* lb = (char*)BsB + d*16384 + (wv<<10);
    #pragma unroll
    for (int i=0;i<4;i++) async16(A8 + paRC[i] + shiftC + cc, la + i*4096);
    #pragma unroll
    for (int i=0;i<4;i++) async16(Bt8 + pbR[i] + ks, lb + i*4096);
    cc += 128; if (cc >= CA){ cc -= CA; tp++; }
    ks += 128;
  };

  const int wm = wv>>1, wn = wv&1;
  const int rA0 = (wm<<6) + (ln&15);
  const int rB0 = (wn<<6) + (ln&15);
  const int xa = ln&7;
  const int q2 = (ln>>4)<<1;
  const int c0 = ((q2    ) ^ xa)<<4;
  const int c1 = ((q2 | 1) ^ xa)<<4;

  stage(0);
  for (int t=0; t<NS; ++t) {
    asm volatile("s_waitcnt vmcnt(0)\ns_barrier" ::: "memory");
    if (t+1 < NS) stage((t+1)&1);

    const char* as_ = (const char*)AsB + (t&1)*16384;
    const char* bs_ = (const char*)BsB + (t&1)*16384;
    i32x8 af[4], bfr[4];
    #pragma unroll
    for (int f=0; f<4; f++){
      const char* p = as_ + ((rA0 + (f<<4))<<7);
      ((i32x4*)&af[f])[0] = *(const i32x4*)(p + c0);
      ((i32x4*)&af[f])[1] = *(const i32x4*)(p + c1);
    }
    #pragma unroll
    for (int f=0; f<4; f++){
      const char* p = bs_ + ((rB0 + (f<<4))<<7);
      ((i32x4*)&bfr[f])[0] = *(const i32x4*)(p + c0);
      ((i32x4*)&bfr[f])[1] = *(const i32x4*)(p + c1);
    }
    __builtin_amdgcn_s_setprio(1);
    #pragma unroll
    for (int mf=0; mf<4; mf++)
      #pragma unroll
      for (int nf=0; nf<4; nf++)
        acc[mf][nf] = __builtin_amdgcn_mfma_scale_f32_16x16x128_f8f6f4(
            af[mf], bfr[nf], acc[mf][nf], 0, 0, 0, 127, 0, 122);
    __builtin_amdgcn_s_setprio(0);
  }
}

// gates GEMM (r11 champion): bf16 out stride 512 + bias.
template<int CA, int NS>
__global__ __launch_bounds__(256)
void conv_g8(const unsigned char* __restrict__ A8,
             const unsigned char* __restrict__ Bt8,
             const float* __restrict__ bias, bf16* __restrict__ outB)
{
  __shared__ alignas(16) unsigned char As[2][16384];
  __shared__ alignas(16) unsigned char Bs[2][16384];
  const int m0 = blockIdx.x<<7, n0 = blockIdx.y<<7;
  f32x4 acc[4][4] = {};
  g8_core<CA,NS>(A8, Bt8, m0, n0, &As[0][0], &Bs[0][0], acc);

  const int tid = threadIdx.x;
  const int wv = tid>>6, ln = tid&63;
  const int mb = m0 + ((wv>>1)<<6);
  const int nb = n0 + ((wv&1)<<6);
  const int ml = (ln>>4)<<2;
  const int nl = ln&15;
  #pragma unroll
  for (int mf=0; mf<4; mf++)
    #pragma unroll
    for (int j=0; j<4; j++) {
      const int m = mb + (mf<<4) + ml + j;
      #pragma unroll
      for (int nf=0; nf<4; nf++) {
        const int n = nb + (nf<<4) + nl;
        outB[((long)m<<9) + n] = __float2bfloat16(acc[mf][nf][j] + bias[n]);
      }
    }
}

// merged fp8 T-convs (pure GEMM now; wrc lives in lstm_wrc_k):
// z=0 decT+prior: n<352 -> sDec8 (+tb(n<327)+ST) ; n>=384 -> PriorO f32 (+pb)
// z=1 encT:       n<416 -> sEnc8 (+tb(n<394)+ST+hDec(n<128))
__global__ __launch_bounds__(256)
void conv_tp8(const unsigned char* __restrict__ h8Dec,
              const unsigned char* __restrict__ h8Enc,
              const unsigned char* __restrict__ Bt8DP,
              const unsigned char* __restrict__ Bt8EncT,
              const float* __restrict__ dec_tb, const float* __restrict__ prior_b,
              const float* __restrict__ enc_tb,
              float* __restrict__ PriorO,
              unsigned char* __restrict__ sDec8, const bf16* __restrict__ STdec,
              unsigned char* __restrict__ sEnc8, const bf16* __restrict__ STenc,
              const bf16* __restrict__ hDecB)
{
  __shared__ alignas(16) unsigned char As[2][16384];
  __shared__ alignas(16) unsigned char Bs[2][16384];
  const int z = blockIdx.z;
  const int m0 = blockIdx.x<<7, n0 = blockIdx.y<<7;
  f32x4 acc[4][4] = {};
  if (z == 0) g8_core<128,25>(h8Dec, Bt8DP,   m0, n0, &As[0][0], &Bs[0][0], acc);
  else        g8_core<128,25>(h8Enc, Bt8EncT, m0, n0, &As[0][0], &Bs[0][0], acc);

  const int tid = threadIdx.x;
  const int wv = tid>>6, ln = tid&63;
  const int mb = m0 + ((wv>>1)<<6);
  const int nb = n0 + ((wv&1)<<6);
  const int ml = (ln>>4)<<2;
  const int nl = ln&15;
  #pragma unroll
  for (int mf=0; mf<4; mf++)
    #pragma unroll
    for (int j=0; j<4; j++) {
      const int m = mb + (mf<<4) + ml + j;
      const long pI = pidx_(m);
      #pragma unroll
      for (int nf=0; nf<4; nf++) {
        const int n = nb + (nf<<4) + nl;
        const float v = acc[mf][nf][j];
        if (z == 0) {
          if (n < 352) {
            float b  = (n < 327) ? dec_tb[n] : 0.f;
            float st = __bfloat162float(STdec[(long)m*352 + n]);
            sDec8[pI*352 + n] = f2fp8(v + b + st);
          } else if (n >= 384) {
            PriorO[((long)m<<7) + (n-384)] = v + prior_b[n-384];
          }
        } else {
          if (n < 416) {
            float b  = (n < 394) ? enc_tb[n] : 0.f;
            float st = __bfloat162float(STenc[(long)m*416 + n]);
            float e  = (n < 128) ? __bfloat162float(hDecB[(pI<<7) + n]) : 0.f;
            sEnc8[pI*416 + n] = f2fp8(v + b + st + e);
          }
        }
      }
    }
}

// ---------------------------------------------------------------------------
// r7-proven 8-wave bf16 conv body — used only by conv_post.
// ---------------------------------------------------------------------------
template<int CA, int EPI>
DEVI void conv_body(const bf16* __restrict__ A, const bf16* __restrict__ Bt,
                    bf16* __restrict__ outB,
                    int s0, int s1, int m0, int n0,
                    bf16* AsBase, bf16* BsBase)
{
  constexpr int Kp = 25*CA;
  const int NS = s1 - s0;

  const int tid = threadIdx.x;
  const int wv = tid>>6, ln = tid&63;

  const int rA = tid>>2;
  const int qs = ((tid&3) ^ ((rA>>1)&3))<<3;
  const int mA0 = m0 + rA, mA1 = m0 + 128 + rA;
  const long paA0 = ((long)(((mA0>>8)*20 + ((mA0>>4)&15))*20 + (mA0&15)))*CA + qs;
  const long paA1 = ((long)(((mA1>>8)*20 + ((mA1>>4)&15))*20 + (mA1&15)))*CA + qs;
  const long pbB  = (long)(n0 + rA)*Kp + qs;

  int kk0 = s0*32;
  int c0 = kk0 % CA;
  int tap = kk0 / CA;
  int kh = tap/5, kw = tap%5;
  int ks = kk0;

  auto stage = [&](int d){
    const long sh = (long)(kh*20 + kw)*CA + c0;
    char* la = (char*)AsBase + d*16384 + (wv<<10);
    char* lb = (char*)BsBase + d*8192  + (wv<<10);
    async16(A + paA0 + sh, la);
    async16(A + paA1 + sh, la + 8192);
    async16(Bt + pbB + ks, lb);
    ks += 32;
    c0 += 32; if (c0==CA){ c0=0; if(++kw==5){kw=0; ++kh;} }
  };

  f32x4 acc[4][4] = {};
  const int wm = wv>>1, wn = wv&1;
  const int rowA = (wm<<6) + (ln&15);
  const int rowB = (wn<<6) + (ln&15);
  const int kqA = (((ln>>4) ^ ((rowA>>1)&3))<<4);
  const int kqB = (((ln>>4) ^ ((rowB>>1)&3))<<4);

  stage(0); stage(1);
  int bc = 0, bs = 2;
  for (int t=0; t<NS; ++t) {
    if (t+1 < NS) waitbar<3>();
    else          waitbar<0>();
    if (t+2 < NS) stage(bs);

    const char* as_ = (const char*)AsBase + bc*16384;
    const char* bs_ = (const char*)BsBase + bc*8192;
    short8 af[4], bfr[4];
    #pragma unroll
    for (int mf=0; mf<4; mf++)
      af[mf] = *(const short8*)(as_ + ((rowA + (mf<<4))<<6) + kqA);
    #pragma unroll
    for (int nf=0; nf<4; nf++)
      bfr[nf] = *(const short8*)(bs_ + ((rowB + (nf<<4))<<6) + kqB);
    __builtin_amdgcn_s_setprio(1);
    #pragma unroll
    for (int mf=0; mf<4; mf++)
      #pragma unroll
      for (int nf=0; nf<4; nf++)
        acc[mf][nf] = __builtin_amdgcn_mfma_f32_16x16x32_bf16(af[mf], bfr[nf], acc[mf][nf], 0,0,0);
    __builtin_amdgcn_s_setprio(0);
    bc = (bc==2)?0:bc+1; bs = (bs==2)?0:bs+1;
  }

  const int mb = m0 + (wm<<6);
  const int nb = n0 + (wn<<6);
  const int ml = (ln>>4)<<2;
  const int nl = ln&15;
  #pragma unroll
  for (int mf=0; mf<4; mf++)
    #pragma unroll
    for (int j=0; j<4; j++) {
      const int m = mb + (mf<<4) + ml + j;
      #pragma unroll
      for (int nf=0; nf<4; nf++) {
        const int n = nb + (nf<<4) + nl;
        outB[((long)m<<7) + n] = __float2bfloat16(acc[mf][nf][j]);
      }
    }
}

// post GEMM split-K=4: grid (64,1,4); partial planes of 16384x128 bf16.
__global__ __launch_bounds__(512)
void conv_post(const bf16* __restrict__ hEnc, const bf16* __restrict__ BtPost,
               bf16* __restrict__ PP)
{
  __shared__ alignas(16) bf16 As[3][256*32];
  __shared__ alignas(16) bf16 Bs[3][128*32];
  const int z = blockIdx.z;
  conv_body<128,6>(hEnc, BtPost, PP + (long)z*MTOT*128,
                   z*25, z*25+25, blockIdx.x<<8, 0, &As[0][0], &Bs[0][0]);
}

// OIHW f32 -> Bt[n=o][k=(kh*5+kw)*CA + c] bf16, rows o>=O / cols c>=I zeroed.
__global__ void repack_w_k(const float* __restrict__ w, bf16* __restrict__ Bt,
                           int O, int I, int CA, long total)
{
  long e = (long)blockIdx.x*256 + threadIdx.x;
  if (e >= total) return;
  const int Kp = 25*CA;
  int o = (int)(e / Kp);
  int k = (int)(e % Kp);
  int blk = k / CA, c = k % CA;
  float v = 0.f;
  if (o < O && c < I) v = w[((long)o*I + c)*25 + blk];
  Bt[e] = __float2bfloat16(v);
}

// fp8 repack with x32 scale (undone by MFMA scale_b = 2^-5), K padded to Kp8.
__global__ void repack_w8_k(const float* __restrict__ w, unsigned char* __restrict__ Bt,
                            int O, int I, int CA, int Kp8, long total)
{
  long e = (long)blockIdx.x*256 + threadIdx.x;
  if (e >= total) return;
  int o = (int)(e / Kp8);
  int k = (int)(e % Kp8);
  float v = 0.f;
  if (k < 25*CA) {
    int blk = k / CA, c = k % CA;
    if (o < O && c < I) v = w[((long)o*I + c)*25 + blk] * 32.0f;
  }
  Bt[e] = f2fp8(v);
}

// Wcomb[c][pix*3+o] = sum_m write_w[c,m,ki,kj] * obs_w[o,m]   (pix = ki*4+kj)
__global__ void wcomb_k(const float* __restrict__ ww, const float* __restrict__ ow,
                        float* __restrict__ Wc)
{
  int idx = blockIdx.x*256 + threadIdx.x;
  if (idx >= 128*48) return;
  int c = idx / 48, rst = idx % 48;
  int pix = rst / 3, o = rst % 3;
  int ki = pix >> 2, kj = pix & 3;
  float a = 0.f;
  for (int mm=0; mm<128; mm++)
    a += ww[(((long)c*128 + mm)*4 + ki)*4 + kj] * ow[o*128 + mm];
  Wc[idx] = a;
}

// xr = conv(x, read_w, stride 4), xr[m*3+o]
__global__ void xr_k(const float* __restrict__ x, const float* __restrict__ rw,
                     float* __restrict__ xr)
{
  int idx = blockIdx.x*256 + threadIdx.x;
  if (idx >= MTOT*3) return;
  int m = idx / 3, o = idx % 3;
  int nb = m>>8, iy=(m>>4)&15, ix=m&15;
  float a = 0.f;
  for (int c=0;c<3;c++)
    for (int kh=0;kh<4;kh++)
      for (int kw=0;kw<4;kw++)
        a += x[((long)(nb*3+c)*64 + (iy*4+kh))*64 + (ix*4+kw)] * rw[((o*3+c)*4+kh)*4+kw];
  xr[idx] = a;
}

// static concat part for enc: channels 128..393 of ST_enc (stride 416)
__global__ void st_enc_k(const float* __restrict__ xr, const float* __restrict__ v,
                         const float* __restrict__ r, bf16* __restrict__ ST)
{
  long g = (long)blockIdx.x*256 + threadIdx.x;
  if (g >= (long)MTOT*266) return;
  int m = (int)(g / 266), ch = (int)(g % 266);
  int nb = m>>8, sp = m&255;
  float val;
  if (ch < 3)       val = xr[m*3 + ch];
  else if (ch < 10) val = v[nb*7 + ch - 3];
  else              val = r[((long)nb*256 + (ch-10))*256 + sp];
  ST[(long)m*416 + 128 + ch] = __float2bfloat16(val);
}

// static concat part for dec: channels 64..326 of ST_dec (stride 352)
__global__ void st_dec_k(const float* __restrict__ v, const float* __restrict__ r,
                         bf16* __restrict__ ST)
{
  long g = (long)blockIdx.x*256 + threadIdx.x;
  if (g >= (long)MTOT*263) return;
  int m = (int)(g / 263), ch = (int)(g % 263);
  int nb = m>>8, sp = m&255;
  float val;
  if (ch < 7) val = v[nb*7 + ch];
  else        val = r[((long)nb*256 + (ch-7))*256 + sp];
  ST[(long)m*352 + 64 + ch] = __float2bfloat16(val);
}

// LSTM core: 8 channels per thread, vectorized loads/stores.
DEVI void lstm8_(const bf16* __restrict__ gates, float* __restrict__ cbuf,
                 bf16* __restrict__ hpad, unsigned char* __restrict__ h8,
                 int m, int c0, float* hout)
{
  long gb = ((long)m<<9) + c0;
  short8 gf = *(const short8*)(gates + gb);
  short8 gi = *(const short8*)(gates + gb + 128);
  short8 go = *(const short8*)(gates + gb + 256);
  short8 gs = *(const short8*)(gates + gb + 384);
  float* cb = cbuf + ((long)m<<7) + c0;
  f32x4 cv0 = *(f32x4*)cb;
  f32x4 cv1 = *(f32x4*)(cb+4);
  short8 hh;
  #pragma unroll
  for (int j=0;j<8;j++){
    float f = s2f(gf[j]);
    float i = s2f(gi[j]);
    float o = s2f(go[j]);
    float s = s2f(gs[j]);
    float cell = sigm_(f)*((j<4)?cv0[j]:cv1[j-4]) + sigm_(i)*tanhf(s);
    if (j<4) cv0[j]=cell; else cv1[j-4]=cell;
    float h = sigm_(o)*tanhf(cell);
    hout[j] = h;
    bf16 hb = __float2bfloat16(h);
    hh[j] = __builtin_bit_cast(short, hb);
  }
  *(f32x4*)cb = cv0;
  *(f32x4*)(cb+4) = cv1;
  long hp = (pidx_(m)<<7) + c0;
  *(short8*)(hpad + hp) = hh;
  int w0 = __builtin_amdgcn_cvt_pk_fp8_f32(hout[0], hout[1], 0, false);
  w0 = __builtin_amdgcn_cvt_pk_fp8_f32(hout[2], hout[3], w0, true);
  int w1 = __builtin_amdgcn_cvt_pk_fp8_f32(hout[4], hout[5], 0, false);
  w1 = __builtin_amdgcn_cvt_pk_fp8_f32(hout[6], hout[7], w1, true);
  i32x2 pw; pw[0]=w0; pw[1]=w1;
  *(i32x2*)(h8 + hp) = pw;
}

// enc LSTM: grid 1024 x 256 threads, 16 m x 128 c per block.
__global__ __launch_bounds__(256)
void lstm_k(const bf16* __restrict__ gates, float* __restrict__ cbuf,
            bf16* __restrict__ hpad, unsigned char* __restrict__ h8)
{
  const int tid = threadIdx.x;
  const int m = (blockIdx.x<<4) + (tid>>4);
  const int c0 = (tid&15)<<3;
  float h[8];
  lstm8_(gates, cbuf, hpad, h8, m, c0, h);
}

// dec LSTM + fused wrc canvas accumulate (h stays in registers/LDS; covers
// h^1..h^8 across the 8 iterations -> no standalone wrc needed).
__global__ __launch_bounds__(256)
void lstm_wrc_k(const bf16* __restrict__ gates, float* __restrict__ cbuf,
                bf16* __restrict__ hpad, unsigned char* __restrict__ h8,
                const float* __restrict__ Wc, float* __restrict__ uc)
{
  __shared__ float Wl[6144];
  __shared__ float hl[16*128];
  const int tid = threadIdx.x;
  for (int i = tid; i < 6144; i += 256) Wl[i] = Wc[i];
  const int mloc = tid>>4;
  const int m = (blockIdx.x<<4) + mloc;
  const int c0 = (tid&15)<<3;
  float h[8];
  lstm8_(gates, cbuf, hpad, h8, m, c0, h);
  #pragma unroll
  for (int j=0;j<8;j++) hl[(mloc<<7) + c0 + j] = h[j];
  __syncthreads();

  // wrc: thread = (mloc, pix). hl reads broadcast; Wl conflict-light.
  const int pix = tid&15;
  const float* hrow = hl + (mloc<<7);
  float a0=0.f, a1=0.f, a2=0.f;
  #pragma unroll 4
  for (int c=0;c<128;c++) {
    float hv = hrow[c];
    const float* wl = Wl + c*48 + pix*3;
    a0 += hv*wl[0]; a1 += hv*wl[1]; a2 += hv*wl[2];
  }
  const int nb = m>>8, iy=(m>>4)&15, ix=m&15;
  const int ki = pix>>2, kj = pix&3;
  long ob = ((long)((nb<<6) + (iy<<2) + ki)*64 + (ix<<2) + kj)*3;
  uc[ob+0] += a0; uc[ob+1] += a1; uc[ob+2] += a2;
}

// z = q_mu + exp(0.5 q_lv)*eps (q = 4 post partials + bias); ADD z into
// fp8 sDec ch 0..63 ; KL partial per block.
__global__ void zkl4_k(const bf16* __restrict__ PP, const float* __restrict__ pb,
                       const float* __restrict__ prior, const float* __restrict__ eps_t,
                       unsigned char* __restrict__ sDec8, float* __restrict__ part)
{
  __shared__ float wsum[4];
  const long PL = (long)MTOT*128;
  int idx = blockIdx.x*256 + threadIdx.x;   // exactly MTOT*64
  int m = idx >> 6, c = idx & 63;
  float qm = pb[c], ql = pb[64 + c];
  #pragma unroll
  for (int z=0; z<4; ++z) {
    qm += __bfloat162float(PP[z*PL + ((long)m<<7) + c]);
    ql += __bfloat162float(PP[z*PL + ((long)m<<7) + 64 + c]);
  }
  long pbx = (long)m << 7;
  float pm = prior[pbx + c], pl = prior[pbx + 64 + c];
  int nb = m>>8, sp = m&255;
  float e = eps_t[((long)nb*64 + c)*256 + sp];
  float z = qm + expf(0.5f*ql)*e;
  long so = pidx_(m)*352 + c;
  sDec8[so] = f2fp8(fp82f(sDec8[so]) + z);
  float kl = expf(ql - pl) + (pm-qm)*(pm-qm)*expf(-pl) - 1.f + (pl - ql);
  #pragma unroll
  for (int off=32; off>0; off>>=1) kl += __shfl_down(kl, off);
  if ((threadIdx.x & 63) == 0) wsum[threadIdx.x >> 6] = kl;
  __syncthreads();
  if (threadIdx.x == 0)
    part[blockIdx.x] = wsum[0] + wsum[1] + wsum[2] + wsum[3];
}

__global__ void canvas_k(const float* __restrict__ uc, const float* __restrict__ ob,
                         float* __restrict__ out)
{
  int idx = blockIdx.x*256 + threadIdx.x;   // exactly 786432, NCHW order
  int x = idx & 63, y = (idx>>6)&63;
  int rem = idx >> 12;
  int o = rem % 3, n = rem / 3;
  float v = uc[((long)((n<<6)+y)*64 + x)*3 + o] + ob[o];
  out[idx] = 1.f/(1.f+expf(-v));
}

// final KL: sum 8*4096 per-block partials, scale, write out[786432]
__global__ void klred_k(const float* __restrict__ part, float* __restrict__ out)
{
  __shared__ float wsum[4];
  float a = 0.f;
  for (int i = threadIdx.x; i < 32768; i += 256) a += part[i];
  #pragma unroll
  for (int off=32; off>0; off>>=1) a += __shfl_down(a, off);
  if ((threadIdx.x & 63) == 0) wsum[threadIdx.x >> 6] = a;
  __syncthreads();
  if (threadIdx.x == 0)
    out[786432] = (wsum[0] + wsum[1] + wsum[2] + wsum[3]) * (0.5f/64.f);
}

// ---------------------------------------------------------------------------
// workspace layout (bytes). fp8 tenants reuse oversized bf16-era slots.
static const long O_BT_POST  = 0;                     // bf16 128*3200*2
static const long O_BT_ENCT  = O_BT_POST  + 819200;   // fp8 512*3200
static const long O_BT_DP    = O_BT_ENCT  + 3276800;  // fp8 512*3200
static const long O_BT_ENCG  = O_BT_DP    + 3276800;  // fp8 512*10496
static const long O_BT_DECG  = O_BT_ENCG  + 10649600; // fp8 512*8832
static const long O_WCOMB    = O_BT_DECG  + 9011200;  // 6144*4
static const long O_XR       = O_WCOMB    + 24576;    // 49152*4
static const long O_KLP      = O_XR       + 196608;   // 32768*4
static const long O_STENC    = O_KLP      + 131072;   // 16384*416*2
static const long O_STDEC    = O_STENC    + 13631488; // 16384*352*2
static const long O_HENC     = O_STDEC    + 11534336; // bf16 25600*128*2
static const long O_HDEC     = O_HENC     + 6553600;
static const long O_SENC     = O_HDEC     + 6553600;  // fp8 25600*416
static const long O_SDEC     = O_SENC     + 21299200; // fp8 25600*352
static const long O_CENC     = O_SDEC     + 18022400; // 16384*128*4
static const long O_CDEC     = O_CENC     + 8388608;
static const long O_PRIOR    = O_CDEC     + 8388608;  // 16384*128*4
static const long O_H8E      = O_PRIOR    + 8388608;  // fp8 25600*128
static const long O_H8D      = O_H8E      + 3276800;
static const long O_PG       = O_H8D      + 3276800;  // Gates 16.7MB + PostP 16.7MB
static const long O_UC       = O_PG       + 33554432; // 786432*4
static const long WS_TOTAL   = O_UC       + 3145728;  // ~174 MB

extern "C" void kernel_launch(void* const* d_in, const int* in_sizes, int n_in,
                              void* d_out, int out_size, void* d_ws, size_t ws_size,
                              hipStream_t stream)
{
  const float* x       = (const float*)d_in[0];
  const float* v       = (const float*)d_in[1];
  const float* r       = (const float*)d_in[2];
  const float* eps     = (const float*)d_in[3];
  const float* read_w  = (const float*)d_in[4];
  const float* write_w = (const float*)d_in[5];
  const float* prior_w = (const float*)d_in[6];
  const float* prior_b = (const float*)d_in[7];
  const float* post_w  = (const float*)d_in[8];
  const float* post_b  = (const float*)d_in[9];
  const float* enc_gw  = (const float*)d_in[10];
  const float* enc_gb  = (const float*)d_in[11];
  const float* enc_tw  = (const float*)d_in[12];
  const float* enc_tb  = (const float*)d_in[13];
  const float* dec_gw  = (const float*)d_in[14];
  const float* dec_gb  = (const float*)d_in[15];
  const float* dec_tw  = (const float*)d_in[16];
  const float* dec_tb  = (const float*)d_in[17];
  const float* obs_w   = (const float*)d_in[18];
  const float* obs_b   = (const float*)d_in[19];

  char* ws = (char*)d_ws;
  bf16* BtPost  = (bf16*)(ws + O_BT_POST);
  unsigned char* Bt8EncT = (unsigned char*)(ws + O_BT_ENCT);
  unsigned char* Bt8DP   = (unsigned char*)(ws + O_BT_DP);
  unsigned char* Bt8EncG = (unsigned char*)(ws + O_BT_ENCG);
  unsigned char* Bt8DecG = (unsigned char*)(ws + O_BT_DECG);
  float* Wcomb  = (float*)(ws + O_WCOMB);
  float* XR     = (float*)(ws + O_XR);
  float* KLpart = (float*)(ws + O_KLP);
  bf16* STenc   = (bf16*)(ws + O_STENC);
  bf16* STdec   = (bf16*)(ws + O_STDEC);
  bf16* hEnc    = (bf16*)(ws + O_HENC);
  bf16* hDec    = (bf16*)(ws + O_HDEC);
  unsigned char* sEnc8 = (unsigned char*)(ws + O_SENC);
  unsigned char* sDec8 = (unsigned char*)(ws + O_SDEC);
  float* cEnc   = (float*)(ws + O_CENC);
  float* cDec   = (float*)(ws + O_CDEC);
  float* PriorO = (float*)(ws + O_PRIOR);
  unsigned char* h8Enc = (unsigned char*)(ws + O_H8E);
  unsigned char* h8Dec = (unsigned char*)(ws + O_H8D);
  bf16* Gates   = (bf16*)(ws + O_PG);
  bf16* PostP   = (bf16*)(ws + O_PG + 16777216);
  float* Ucomb  = (float*)(ws + O_UC);
  float* out    = (float*)d_out;

  size_t clr = (size_t)WS_TOTAL; if (clr > ws_size) clr = ws_size;
  hipMemsetAsync(d_ws, 0, clr, stream);

  // weight repacks
  repack_w_k<<<1600, 256, 0, stream>>>(post_w, BtPost, 128, 128, 128, 128L*3200);
  repack_w8_k<<<6400, 256, 0, stream>>>(enc_tw, Bt8EncT, 394, 128, 128, 3200, 512L*3200);
  repack_w8_k<<<4800, 256, 0, stream>>>(dec_tw, Bt8DP, 327, 128, 128, 3200, 384L*3200);
  repack_w8_k<<<1600, 256, 0, stream>>>(prior_w, Bt8DP + 384L*3200, 128, 128, 128, 3200, 128L*3200);
  repack_w8_k<<<20992, 256, 0, stream>>>(enc_gw, Bt8EncG, 512, 394, 416, 82*128, 512L*10496);
  repack_w8_k<<<17664, 256, 0, stream>>>(dec_gw, Bt8DecG, 512, 327, 352, 69*128, 512L*8832);
  wcomb_k<<<24, 256, 0, stream>>>(write_w, obs_w, Wcomb);
  xr_k<<<192, 256, 0, stream>>>(x, read_w, XR);
  st_enc_k<<<(int)(((long)MTOT*266 + 255)/256), 256, 0, stream>>>(XR, v, r, STenc);
  st_dec_k<<<(int)(((long)MTOT*263 + 255)/256), 256, 0, stream>>>(v, r, STdec);

  for (int t = 0; t < 8; ++t) {
    // merged fp8 T-convs (decT+prior | encT), pure GEMM
    conv_tp8<<<dim3(128,4,2), 256, 0, stream>>>(
        h8Dec, h8Enc, Bt8DP, Bt8EncT, dec_tb, prior_b, enc_tb,
        PriorO, sDec8, STdec, sEnc8, STenc, hDec);
    // enc gates: MX-fp8
    conv_g8<416,82><<<dim3(128,4), 256, 0, stream>>>(sEnc8, Bt8EncG, enc_gb, Gates);
    lstm_k<<<1024, 256, 0, stream>>>(Gates, cEnc, hEnc, h8Enc);
    // post split-K=4 -> partial planes (bf16, accuracy-critical)
    conv_post<<<dim3(64,1,4), 512, 0, stream>>>(hEnc, BtPost, PostP);
    // z (sum partials + bias) -> add into fp8 sDec ch0..63 ; KL partials
    zkl4_k<<<4096, 256, 0, stream>>>(PostP, post_b, PriorO,
                                     eps + (long)t*64*64*256, sDec8,
                                     KLpart + (long)t*4096);
    // dec gates: MX-fp8
    conv_g8<352,69><<<dim3(128,4), 256, 0, stream>>>(sDec8, Bt8DecG, dec_gb, Gates);
    // dec LSTM + fused canvas accumulate (covers h^1..h^8 over the loop)
    lstm_wrc_k<<<1024, 256, 0, stream>>>(Gates, cDec, hDec, h8Dec, Wcomb, Ucomb);
  }

  canvas_k<<<3072, 256, 0, stream>>>(Ucomb, obs_b, out);
  klred_k<<<1, 256, 0, stream>>>(KLpart, out);
}